// Round 1
// baseline (2524.283 us; speedup 1.0000x reference)
//
#include <hip/hip_runtime.h>
#include <hip/hip_bf16.h>

// ---------------------------------------------------------------------------
// ArrowTransformer forward: B=2, S=1024, D=1024, H=16, HD=64, L=6, V=256
// ---------------------------------------------------------------------------

typedef __attribute__((ext_vector_type(8))) short  s8_t;
typedef __attribute__((ext_vector_type(4))) short  s4_t;
typedef __attribute__((ext_vector_type(8))) __bf16 bf8_t;
typedef __attribute__((ext_vector_type(4))) float  f4v;

static __device__ __forceinline__ short f2bf(float f) {
  union { float f; unsigned u; } a; a.f = f;
  unsigned u = a.u;
  u += 0x7fffu + ((u >> 16) & 1u);       // round-to-nearest-even
  return (short)(u >> 16);
}
static __device__ __forceinline__ float bf2f(short s) {
  union { float f; unsigned u; } a;
  a.u = ((unsigned)(unsigned short)s) << 16;
  return a.f;
}
static __device__ __forceinline__ f4v mfma16(s8_t a, s8_t b, f4v c) {
  return __builtin_amdgcn_mfma_f32_16x16x32_bf16(
      __builtin_bit_cast(bf8_t, a), __builtin_bit_cast(bf8_t, b), c, 0, 0, 0);
}

// ---------------------------------------------------------------------------
// Transpose + f32->bf16 convert:  out[c][r] = bf16(in[r][c]);  batch = blockIdx.z
// block (32,8); grid (C/32, R/32, batch)
// ---------------------------------------------------------------------------
__global__ void transpose_bf16(const float* __restrict__ in, short* __restrict__ out,
                               int R, int C) {
  __shared__ float tile[32][33];
  const long zo = (long)blockIdx.z * R * C;
  const int c0 = blockIdx.x * 32, r0 = blockIdx.y * 32;
  const int tx = threadIdx.x, ty = threadIdx.y;
#pragma unroll
  for (int i = 0; i < 4; i++)
    tile[ty + i * 8][tx] = in[zo + (long)(r0 + ty + i * 8) * C + c0 + tx];
  __syncthreads();
#pragma unroll
  for (int i = 0; i < 4; i++)
    out[zo + (long)(c0 + ty + i * 8) * R + r0 + tx] = f2bf(tile[tx][ty + i * 8]);
}

// ---------------------------------------------------------------------------
// Embedding + sinusoidal positional encoding. grid = B*S blocks, 256 threads.
// ---------------------------------------------------------------------------
__global__ __launch_bounds__(256) void embed_kernel(const int* __restrict__ x,
                                                    const float* __restrict__ emb,
                                                    float* __restrict__ h) {
  const int row = blockIdx.x;            // b*S + s
  const int s = row & 1023;
  const int xv = x[row];
  const int c = threadIdx.x << 2;
  const float4 e = *(const float4*)(emb + (long)xv * 1024 + c);
  const float ev[4] = {e.x, e.y, e.z, e.w};
  float out[4];
#pragma unroll
  for (int i = 0; i < 4; i++) {
    const int d = c + i;
    const float par = (float)(d & 1);
    const float rate = expf(-9.210340371976184f * (float)d / 1024.0f) *
                       expf(9.210340371976184f * par / 1024.0f);
    const float pe = sinf((float)s * rate + 1.5707963267948966f * par);
    out[i] = ev[i] * 32.0f + pe;
  }
  float4 o; o.x = out[0]; o.y = out[1]; o.z = out[2]; o.w = out[3];
  *(float4*)(h + (long)row * 1024 + c) = o;
}

// ---------------------------------------------------------------------------
// LayerNorm over D=1024 (no residual). One block per row. In-place safe.
// ---------------------------------------------------------------------------
__global__ __launch_bounds__(256) void ln_kernel(const float* __restrict__ in,
                                                 float* __restrict__ out,
                                                 const float* __restrict__ g,
                                                 const float* __restrict__ be) {
  __shared__ float red[4];
  __shared__ float red2[4];
  const int row = blockIdx.x;
  const int tid = threadIdx.x;
  const int c = tid << 2;
  const float4 xv = *(const float4*)(in + (long)row * 1024 + c);
  float s = xv.x + xv.y + xv.z + xv.w;
#pragma unroll
  for (int off = 1; off < 64; off <<= 1) s += __shfl_xor(s, off);
  const int wave = tid >> 6, lane = tid & 63;
  if (lane == 0) red[wave] = s;
  __syncthreads();
  const float mu = (red[0] + red[1] + red[2] + red[3]) * (1.0f / 1024.0f);
  const float d0 = xv.x - mu, d1 = xv.y - mu, d2 = xv.z - mu, d3 = xv.w - mu;
  float q = d0 * d0 + d1 * d1 + d2 * d2 + d3 * d3;
#pragma unroll
  for (int off = 1; off < 64; off <<= 1) q += __shfl_xor(q, off);
  if (lane == 0) red2[wave] = q;
  __syncthreads();
  const float var = (red2[0] + red2[1] + red2[2] + red2[3]) * (1.0f / 1024.0f);
  const float rs = rsqrtf(var + 1e-6f);
  const float4 gv = *(const float4*)(g + c);
  const float4 bv = *(const float4*)(be + c);
  float4 o;
  o.x = d0 * rs * gv.x + bv.x;
  o.y = d1 * rs * gv.y + bv.y;
  o.z = d2 * rs * gv.z + bv.z;
  o.w = d3 * rs * gv.w + bv.w;
  *(float4*)(out + (long)row * 1024 + c) = o;
}

// ---------------------------------------------------------------------------
// GEMM: C[m][n] = sum_k A[m][k] * BT[n][k] (+bias[n]) (+relu)
// A: f32 (converted to bf16 at staging). BT: bf16 (BT_BF16=1) or f32.
// 128x128 tile, BK=32, 256 threads (4 waves 2x2, each 64x64 via 4x4 MFMA frags).
// Batch via blockIdx.z: offA = (z/batH)*sA1 + (z%batH)*sA2 ; BT += z*sBT ; C += z*sC
// ---------------------------------------------------------------------------
template <int BT_BF16, int OUT_BF16, int RELU>
__global__ __launch_bounds__(256) void gemm_bt(
    const float* __restrict__ A, const void* __restrict__ BTv,
    void* __restrict__ Cv, const float* __restrict__ biasp,
    int K, int lda, int ldb, int ldc,
    int batH, long sA1, long sA2, long sBT, long sC) {
  __shared__ short As[128][40];
  __shared__ short Bs[128][40];

  const int tid = threadIdx.x;
  const int bm = blockIdx.y * 128, bn = blockIdx.x * 128;
  const int z = blockIdx.z;
  A += (long)(z / batH) * sA1 + (long)(z % batH) * sA2;

  const int ar = tid >> 1;
  const int ac = (tid & 1) << 4;
  const float* Ap = A + (long)(bm + ar) * lda + ac;
  const short* Bps = (const short*)BTv + (long)z * sBT + (long)(bn + ar) * ldb + ac;
  const float* Bpf = (const float*)BTv + (long)z * sBT + (long)(bn + ar) * ldb + ac;

  const int lane = tid & 63, wave = tid >> 6;
  const int quad = lane >> 4, l16 = lane & 15;
  const int wm = (wave >> 1) << 6, wn = (wave & 1) << 6;

  f4v acc[4][4];
#pragma unroll
  for (int i = 0; i < 4; i++)
#pragma unroll
    for (int j = 0; j < 4; j++) {
      f4v zz = {0.f, 0.f, 0.f, 0.f};
      acc[i][j] = zz;
    }

  for (int k0 = 0; k0 < K; k0 += 32) {
    {
      alignas(16) short tmp[16];
#pragma unroll
      for (int c4 = 0; c4 < 4; c4++) {
        const float4 t = *(const float4*)(Ap + k0 + c4 * 4);
        tmp[c4 * 4 + 0] = f2bf(t.x); tmp[c4 * 4 + 1] = f2bf(t.y);
        tmp[c4 * 4 + 2] = f2bf(t.z); tmp[c4 * 4 + 3] = f2bf(t.w);
      }
      *(s8_t*)&As[ar][ac] = *(const s8_t*)&tmp[0];
      *(s8_t*)&As[ar][ac + 8] = *(const s8_t*)&tmp[8];
    }
    if (BT_BF16) {
      const s8_t b0 = *(const s8_t*)(Bps + k0);
      const s8_t b1 = *(const s8_t*)(Bps + k0 + 8);
      *(s8_t*)&Bs[ar][ac] = b0;
      *(s8_t*)&Bs[ar][ac + 8] = b1;
    } else {
      alignas(16) short tmp[16];
#pragma unroll
      for (int c4 = 0; c4 < 4; c4++) {
        const float4 t = *(const float4*)(Bpf + k0 + c4 * 4);
        tmp[c4 * 4 + 0] = f2bf(t.x); tmp[c4 * 4 + 1] = f2bf(t.y);
        tmp[c4 * 4 + 2] = f2bf(t.z); tmp[c4 * 4 + 3] = f2bf(t.w);
      }
      *(s8_t*)&Bs[ar][ac] = *(const s8_t*)&tmp[0];
      *(s8_t*)&Bs[ar][ac + 8] = *(const s8_t*)&tmp[8];
    }
    __syncthreads();
    s8_t af[4], bfr[4];
#pragma unroll
    for (int t = 0; t < 4; t++)
      af[t] = *(const s8_t*)&As[wm + t * 16 + l16][quad * 8];
#pragma unroll
    for (int t = 0; t < 4; t++)
      bfr[t] = *(const s8_t*)&Bs[wn + t * 16 + l16][quad * 8];
#pragma unroll
    for (int ti = 0; ti < 4; ti++)
#pragma unroll
      for (int tj = 0; tj < 4; tj++)
        acc[ti][tj] = mfma16(af[ti], bfr[tj], acc[ti][tj]);
    __syncthreads();
  }

  char* Cb = (char*)Cv + (long)z * sC * (OUT_BF16 ? 2 : 4);
#pragma unroll
  for (int ti = 0; ti < 4; ti++) {
#pragma unroll
    for (int tj = 0; tj < 4; tj++) {
      const int n = bn + wn + tj * 16 + l16;
      const float bval = biasp ? biasp[n] : 0.f;
#pragma unroll
      for (int r = 0; r < 4; r++) {
        const int m = bm + wm + ti * 16 + quad * 4 + r;
        float vv = acc[ti][tj][r] + bval;
        if (RELU) vv = fmaxf(vv, 0.f);
        if (OUT_BF16) ((short*)Cb)[(long)m * ldc + n] = f2bf(vv);
        else          ((float*)Cb)[(long)m * ldc + n] = vv;
      }
    }
  }
}

// ---------------------------------------------------------------------------
// Fused attention with online softmax + relative-position (Music Transformer).
// grid (B*H, S/64); 256 threads = 4 waves; wave handles 16 query rows.
// logits[i][j] = (q_i.k_j + (j<=i ? QE[i][S-1-i+j] : 0)) * 0.125
//               + ((j>i || x[b,j]==0) ? -1e9 : 0)
// Full (non-causal-skipped) key sweep to match reference -1e9 semantics exactly.
// ---------------------------------------------------------------------------
__global__ __launch_bounds__(256) void attn_kernel(
    const float* __restrict__ qb, const float* __restrict__ kb,
    const float* __restrict__ vb, const short* __restrict__ QE,
    const int* __restrict__ xids, float* __restrict__ outb) {
  __shared__ short Ks[64][72];      // [key][dim]
  __shared__ short Vt[64][72];      // [dim][key]  (transposed)
  __shared__ short Ps[4][16][72];   // per wave: [row][key]
  __shared__ float kneg[64];

  const int bh = blockIdx.x, b = bh >> 4, hh = bh & 15;
  const int itile = blockIdx.y;
  const int tid = threadIdx.x;
  const int wave = tid >> 6, lane = tid & 63, quad = lane >> 4, l16 = lane & 15;
  const int i0 = itile * 64 + wave * 16;

  // Q fragments (A-operand layout: row = lane&15, k = quad*8 + j)
  s8_t aq[2];
  {
    const float* qp = qb + ((long)(b * 1024 + i0 + l16)) * 1024 + hh * 64 + quad * 8;
#pragma unroll
    for (int ks = 0; ks < 2; ks++) {
      const float4 t0 = *(const float4*)(qp + ks * 32);
      const float4 t1 = *(const float4*)(qp + ks * 32 + 4);
      alignas(16) short tmp[8] = {f2bf(t0.x), f2bf(t0.y), f2bf(t0.z), f2bf(t0.w),
                                  f2bf(t1.x), f2bf(t1.y), f2bf(t1.z), f2bf(t1.w)};
      aq[ks] = *(const s8_t*)tmp;
    }
  }

  f4v o[4];
#pragma unroll
  for (int nt = 0; nt < 4; nt++) { f4v zz = {0.f, 0.f, 0.f, 0.f}; o[nt] = zz; }
  float m_run[4] = {-INFINITY, -INFINITY, -INFINITY, -INFINITY};
  float l_run[4] = {0.f, 0.f, 0.f, 0.f};

  const int jr = tid >> 2, c0 = (tid & 3) << 4;
  const float* kp0 = kb + ((long)(b * 1024 + jr)) * 1024 + hh * 64 + c0;
  const float* vp0 = vb + ((long)(b * 1024 + jr)) * 1024 + hh * 64 + c0;

  for (int j0 = 0; j0 < 1024; j0 += 64) {
    // ---- stage K (row-major) and V (transposed) into LDS, bf16 ----
#pragma unroll
    for (int c4 = 0; c4 < 4; c4++) {
      const float4 tk = *(const float4*)(kp0 + (long)j0 * 1024 + c4 * 4);
      alignas(8) short tmpk[4] = {f2bf(tk.x), f2bf(tk.y), f2bf(tk.z), f2bf(tk.w)};
      *(s4_t*)&Ks[jr][c0 + c4 * 4] = *(const s4_t*)tmpk;
      const float4 tv = *(const float4*)(vp0 + (long)j0 * 1024 + c4 * 4);
      Vt[c0 + c4 * 4 + 0][jr] = f2bf(tv.x);
      Vt[c0 + c4 * 4 + 1][jr] = f2bf(tv.y);
      Vt[c0 + c4 * 4 + 2][jr] = f2bf(tv.z);
      Vt[c0 + c4 * 4 + 3][jr] = f2bf(tv.w);
    }
    if (tid < 64) kneg[tid] = (xids[b * 1024 + j0 + tid] == 0) ? -1e9f : 0.0f;
    __syncthreads();

    // ---- scores: 16x64 block via MFMA, C-layout (row=quad*4+r, col=l16) ----
    f4v sc[4];
#pragma unroll
    for (int nt = 0; nt < 4; nt++) {
      const s8_t k0f = *(const s8_t*)&Ks[nt * 16 + l16][quad * 8];
      const s8_t k1f = *(const s8_t*)&Ks[nt * 16 + l16][32 + quad * 8];
      f4v zz = {0.f, 0.f, 0.f, 0.f};
      zz = mfma16(aq[0], k0f, zz);
      zz = mfma16(aq[1], k1f, zz);
      sc[nt] = zz;
    }

    float p[4][4];
    const int irow = i0 + quad * 4;
#pragma unroll
    for (int nt = 0; nt < 4; nt++) {
      const int j = j0 + nt * 16 + l16;
#pragma unroll
      for (int r = 0; r < 4; r++) {
        const int i = irow + r;
        float s = sc[nt][r];
        if (j <= i) s += bf2f(QE[((long)bh * 1024 + i) * 1024 + (1023 - i + j)]);
        s *= 0.125f;
        s += (j > i) ? -1e9f : kneg[nt * 16 + l16];
        p[nt][r] = s;
      }
    }

    // ---- online softmax update (row stats across the 16 lanes of a quad) ----
    float alpha[4];
#pragma unroll
    for (int r = 0; r < 4; r++) {
      float mx = fmaxf(fmaxf(p[0][r], p[1][r]), fmaxf(p[2][r], p[3][r]));
      mx = fmaxf(mx, __shfl_xor(mx, 1));
      mx = fmaxf(mx, __shfl_xor(mx, 2));
      mx = fmaxf(mx, __shfl_xor(mx, 4));
      mx = fmaxf(mx, __shfl_xor(mx, 8));
      const float mnew = fmaxf(m_run[r], mx);
      alpha[r] = expf(m_run[r] - mnew);
      float ps = 0.f;
#pragma unroll
      for (int nt = 0; nt < 4; nt++) {
        p[nt][r] = expf(p[nt][r] - mnew);
        ps += p[nt][r];
      }
      ps += __shfl_xor(ps, 1);
      ps += __shfl_xor(ps, 2);
      ps += __shfl_xor(ps, 4);
      ps += __shfl_xor(ps, 8);
      l_run[r] = l_run[r] * alpha[r] + ps;
      m_run[r] = mnew;
    }

    // ---- write P (bf16) to LDS (C-layout -> A-layout transform), rescale O ----
#pragma unroll
    for (int nt = 0; nt < 4; nt++) {
#pragma unroll
      for (int r = 0; r < 4; r++) {
        Ps[wave][quad * 4 + r][nt * 16 + l16] = f2bf(p[nt][r]);
        o[nt][r] *= alpha[r];
      }
    }

    // ---- O += P @ V ----
#pragma unroll
    for (int ks = 0; ks < 2; ks++) {
      const s8_t ap = *(const s8_t*)&Ps[wave][l16][ks * 32 + quad * 8];
#pragma unroll
      for (int nt = 0; nt < 4; nt++) {
        const s8_t vf = *(const s8_t*)&Vt[nt * 16 + l16][ks * 32 + quad * 8];
        o[nt] = mfma16(ap, vf, o[nt]);
      }
    }
    __syncthreads();
  }

  // ---- epilogue: O / l ----
#pragma unroll
  for (int nt = 0; nt < 4; nt++) {
#pragma unroll
    for (int r = 0; r < 4; r++) {
      const int i = i0 + quad * 4 + r;
      outb[((long)(b * 1024 + i)) * 1024 + hh * 64 + nt * 16 + l16] =
          o[nt][r] / l_run[r];
    }
  }
}

// ---------------------------------------------------------------------------
extern "C" void kernel_launch(void* const* d_in, const int* in_sizes, int n_in,
                              void* d_out, int out_size, void* d_ws, size_t ws_size,
                              hipStream_t stream) {
  const int*   x   = (const int*)d_in[0];
  const float* emb = (const float*)d_in[1];
  const float* Wq  = (const float*)d_in[2];
  const float* bq  = (const float*)d_in[3];
  const float* Wk  = (const float*)d_in[4];
  const float* bk  = (const float*)d_in[5];
  const float* Wv  = (const float*)d_in[6];
  const float* bv  = (const float*)d_in[7];
  const float* Wo  = (const float*)d_in[8];
  const float* bo  = (const float*)d_in[9];
  const float* W1  = (const float*)d_in[10];
  const float* b1  = (const float*)d_in[11];
  const float* W2  = (const float*)d_in[12];
  const float* b2  = (const float*)d_in[13];
  const float* g1  = (const float*)d_in[14];
  const float* be1 = (const float*)d_in[15];
  const float* g2  = (const float*)d_in[16];
  const float* be2 = (const float*)d_in[17];
  const float* E   = (const float*)d_in[18];
  const float* Wf  = (const float*)d_in[19];
  const float* bfv = (const float*)d_in[20];

  char* p = (char*)d_ws;
  auto alloc = [&](size_t bytes) {
    char* r = p;
    p += (bytes + 255) & ~(size_t)255;
    return r;
  };
  float* h    = (float*)alloc(2048ull * 1024 * 4);
  float* qbuf = (float*)alloc(2048ull * 1024 * 4);
  float* kbuf = (float*)alloc(2048ull * 1024 * 4);
  float* vbuf = (float*)alloc(2048ull * 1024 * 4);
  float* attn = (float*)alloc(2048ull * 1024 * 4);
  float* tmp  = (float*)alloc(2048ull * 1024 * 4);
  float* mid  = (float*)alloc(2048ull * 512 * 4);
  short* QEb  = (short*)alloc(32ull * 1024 * 1024 * 2);
  short* WqT  = (short*)alloc(6ull * 1024 * 1024 * 2);
  short* WkT  = (short*)alloc(6ull * 1024 * 1024 * 2);
  short* WvT  = (short*)alloc(6ull * 1024 * 1024 * 2);
  short* WoT  = (short*)alloc(6ull * 1024 * 1024 * 2);
  short* W1T  = (short*)alloc(6ull * 512 * 1024 * 2);
  short* W2T  = (short*)alloc(6ull * 512 * 1024 * 2);
  short* WfT  = (short*)alloc(256ull * 1024 * 2);

  const dim3 tb(32, 8);
  transpose_bf16<<<dim3(32, 32, 6), tb, 0, stream>>>(Wq, WqT, 1024, 1024);
  transpose_bf16<<<dim3(32, 32, 6), tb, 0, stream>>>(Wk, WkT, 1024, 1024);
  transpose_bf16<<<dim3(32, 32, 6), tb, 0, stream>>>(Wv, WvT, 1024, 1024);
  transpose_bf16<<<dim3(32, 32, 6), tb, 0, stream>>>(Wo, WoT, 1024, 1024);
  transpose_bf16<<<dim3(16, 32, 6), tb, 0, stream>>>(W1, W1T, 1024, 512);
  transpose_bf16<<<dim3(32, 16, 6), tb, 0, stream>>>(W2, W2T, 512, 1024);
  transpose_bf16<<<dim3(8, 32, 1), tb, 0, stream>>>(Wf, WfT, 1024, 256);

  embed_kernel<<<2048, 256, 0, stream>>>(x, emb, h);

  for (int l = 0; l < 6; l++) {
    const long wOff = (long)l * 1024 * 1024;
    const long w12Off = (long)l * 512 * 1024;
    // Q, K, V projections
    gemm_bt<1, 0, 0><<<dim3(8, 16, 1), 256, 0, stream>>>(
        h, WqT + wOff, qbuf, bq + l * 1024, 1024, 1024, 1024, 1024, 1, 0, 0, 0, 0);
    gemm_bt<1, 0, 0><<<dim3(8, 16, 1), 256, 0, stream>>>(
        h, WkT + wOff, kbuf, bk + l * 1024, 1024, 1024, 1024, 1024, 1, 0, 0, 0, 0);
    gemm_bt<1, 0, 0><<<dim3(8, 16, 1), 256, 0, stream>>>(
        h, WvT + wOff, vbuf, bv + l * 1024, 1024, 1024, 1024, 1024, 1, 0, 0, 0, 0);
    // QE[bh][i][m] = q[b,i,hh*64+:] . E[l][m][:]   (batched over bh, bf16 out)
    gemm_bt<0, 1, 0><<<dim3(8, 8, 32), 256, 0, stream>>>(
        qbuf, E + (long)l * 1024 * 64, QEb, nullptr,
        64, 1024, 64, 1024, 16, (long)1024 * 1024, 64, 0, (long)1024 * 1024);
    // fused attention
    attn_kernel<<<dim3(32, 16), 256, 0, stream>>>(qbuf, kbuf, vbuf, QEb, x, attn);
    // output projection + LN
    gemm_bt<1, 0, 0><<<dim3(8, 16, 1), 256, 0, stream>>>(
        attn, WoT + wOff, tmp, bo + l * 1024, 1024, 1024, 1024, 1024, 1, 0, 0, 0, 0);
    ln_kernel<<<2048, 256, 0, stream>>>(tmp, tmp, g1 + l * 1024, be1 + l * 1024);
    // FFN
    gemm_bt<1, 0, 1><<<dim3(4, 16, 1), 256, 0, stream>>>(
        tmp, W1T + w12Off, mid, b1 + l * 512, 1024, 1024, 1024, 512, 1, 0, 0, 0, 0);
    gemm_bt<1, 0, 0><<<dim3(8, 16, 1), 256, 0, stream>>>(
        mid, W2T + w12Off, h, b2 + l * 1024, 512, 512, 512, 1024, 1, 0, 0, 0, 0);
    ln_kernel<<<2048, 256, 0, stream>>>(h, h, g2 + l * 1024, be2 + l * 1024);
  }
  // final projection -> d_out (f32)
  gemm_bt<1, 0, 0><<<dim3(2, 16, 1), 256, 0, stream>>>(
      h, WfT, (float*)d_out, bfv, 1024, 1024, 1024, 256, 1, 0, 0, 0, 0);
}

// Round 2
// 1700.769 us; speedup vs baseline: 1.4842x; 1.4842x over previous
//
#include <hip/hip_runtime.h>
#include <hip/hip_bf16.h>

// ---------------------------------------------------------------------------
// ArrowTransformer forward: B=2, S=1024, D=1024, H=16, HD=64, L=6, V=256
// Round 1: bf16 activations everywhere, global_load_lds GEMM (m97 structure),
// fused QKV projection, causal tile skipping in attention (+pad fallback),
// causal block skipping in the QE GEMM.
// ---------------------------------------------------------------------------

typedef __attribute__((ext_vector_type(8))) short  s8_t;
typedef __attribute__((ext_vector_type(4))) short  s4_t;
typedef __attribute__((ext_vector_type(8))) __bf16 bf8_t;
typedef __attribute__((ext_vector_type(4))) float  f4v;

static __device__ __forceinline__ short f2bf(float f) {
  union { float f; unsigned u; } a; a.f = f;
  unsigned u = a.u;
  u += 0x7fffu + ((u >> 16) & 1u);       // round-to-nearest-even
  return (short)(u >> 16);
}
static __device__ __forceinline__ float bf2f(short s) {
  union { float f; unsigned u; } a;
  a.u = ((unsigned)(unsigned short)s) << 16;
  return a.f;
}
static __device__ __forceinline__ f4v mfma16(s8_t a, s8_t b, f4v c) {
  return __builtin_amdgcn_mfma_f32_16x16x32_bf16(
      __builtin_bit_cast(bf8_t, a), __builtin_bit_cast(bf8_t, b), c, 0, 0, 0);
}
// async global->LDS, 16 B per lane; LDS dest is wave-uniform base + lane*16
static __device__ __forceinline__ void gld16(const short* g, short* l) {
  __builtin_amdgcn_global_load_lds(
      (const __attribute__((address_space(1))) void*)g,
      (__attribute__((address_space(3))) void*)l, 16, 0, 0);
}

// ---------------------------------------------------------------------------
// Transpose + f32->bf16: out[z*outBS + (outRowOff + c)*R + r] = bf16(in[z][r][c])
// block (32,8); grid (C/32, R/32, batch)
// ---------------------------------------------------------------------------
__global__ void transpose_bf16(const float* __restrict__ in, short* __restrict__ out,
                               int R, int C, long outBS, int outRowOff) {
  __shared__ float tile[32][33];
  const long zi = (long)blockIdx.z * R * C;
  out += (long)blockIdx.z * outBS + (long)outRowOff * R;
  const int c0 = blockIdx.x * 32, r0 = blockIdx.y * 32;
  const int tx = threadIdx.x, ty = threadIdx.y;
#pragma unroll
  for (int i = 0; i < 4; i++)
    tile[ty + i * 8][tx] = in[zi + (long)(r0 + ty + i * 8) * C + c0 + tx];
  __syncthreads();
#pragma unroll
  for (int i = 0; i < 4; i++)
    out[(long)(c0 + ty + i * 8) * R + r0 + tx] = f2bf(tile[tx][ty + i * 8]);
}

// f32 -> bf16 elementwise (n multiple of 1024); grid n/1024 blocks x 256
__global__ __launch_bounds__(256) void cvt_bf16(const float* __restrict__ in,
                                                short* __restrict__ out) {
  const long i = ((long)blockIdx.x * 256 + threadIdx.x) * 4;
  const float4 t = *(const float4*)(in + i);
  s4_t o = {f2bf(t.x), f2bf(t.y), f2bf(t.z), f2bf(t.w)};
  *(s4_t*)(out + i) = o;
}

// concat [bq|bk|bv] per layer -> qkvB[6][3072]; grid 72 x 256
__global__ void qkv_bias_kernel(const float* __restrict__ bq, const float* __restrict__ bk,
                                const float* __restrict__ bv, float* __restrict__ out) {
  const int idx = blockIdx.x * 256 + threadIdx.x;
  const int l = idx / 3072, n = idx % 3072;
  float v = (n < 1024) ? bq[l * 1024 + n]
          : (n < 2048) ? bk[l * 1024 + n - 1024]
                       : bv[l * 1024 + n - 2048];
  out[idx] = v;
}

// first non-pad position per batch; grid 2 x 64
__global__ void fnp_kernel(const int* __restrict__ x, int* __restrict__ fnp) {
  const int b = blockIdx.x, lane = threadIdx.x;
  int first = 1024;
  for (int j0 = 0; j0 < 1024; j0 += 64) {
    unsigned long long m = __ballot(x[b * 1024 + j0 + lane] != 0);
    if (m) { first = j0 + __ffsll(m) - 1; break; }
  }
  if (lane == 0) fnp[b] = first;
}

// ---------------------------------------------------------------------------
// Embedding + sinusoidal positional encoding -> bf16. grid B*S x 256.
// ---------------------------------------------------------------------------
__global__ __launch_bounds__(256) void embed_kernel(const int* __restrict__ x,
                                                    const float* __restrict__ emb,
                                                    short* __restrict__ h) {
  const int row = blockIdx.x;
  const int s = row & 1023;
  const int xv = x[row];
  const int c = threadIdx.x << 2;
  const float4 e = *(const float4*)(emb + (long)xv * 1024 + c);
  const float ev[4] = {e.x, e.y, e.z, e.w};
  s4_t o;
#pragma unroll
  for (int i = 0; i < 4; i++) {
    const int d = c + i;
    const float par = (float)(d & 1);
    const float rate = expf(-9.210340371976184f * (float)d / 1024.0f) *
                       expf(9.210340371976184f * par / 1024.0f);
    const float pe = sinf((float)s * rate + 1.5707963267948966f * par);
    o[i] = f2bf(ev[i] * 32.0f + pe);
  }
  *(s4_t*)(h + (long)row * 1024 + c) = o;
}

// ---------------------------------------------------------------------------
// LayerNorm over D=1024, bf16 in/out. One block per row. In-place safe.
// ---------------------------------------------------------------------------
__global__ __launch_bounds__(256) void ln_kernel(const short* __restrict__ in,
                                                 short* __restrict__ out,
                                                 const float* __restrict__ g,
                                                 const float* __restrict__ be) {
  __shared__ float red[4];
  __shared__ float red2[4];
  const int row = blockIdx.x;
  const int tid = threadIdx.x;
  const int c = tid << 2;
  const s4_t xv = *(const s4_t*)(in + (long)row * 1024 + c);
  const float x0 = bf2f(xv[0]), x1 = bf2f(xv[1]), x2 = bf2f(xv[2]), x3 = bf2f(xv[3]);
  float s = x0 + x1 + x2 + x3;
#pragma unroll
  for (int off = 1; off < 64; off <<= 1) s += __shfl_xor(s, off);
  const int wave = tid >> 6, lane = tid & 63;
  if (lane == 0) red[wave] = s;
  __syncthreads();
  const float mu = (red[0] + red[1] + red[2] + red[3]) * (1.0f / 1024.0f);
  const float d0 = x0 - mu, d1 = x1 - mu, d2 = x2 - mu, d3 = x3 - mu;
  float q = d0 * d0 + d1 * d1 + d2 * d2 + d3 * d3;
#pragma unroll
  for (int off = 1; off < 64; off <<= 1) q += __shfl_xor(q, off);
  if (lane == 0) red2[wave] = q;
  __syncthreads();
  const float var = (red2[0] + red2[1] + red2[2] + red2[3]) * (1.0f / 1024.0f);
  const float rs = rsqrtf(var + 1e-6f);
  const float4 gv = *(const float4*)(g + c);
  const float4 bv = *(const float4*)(be + c);
  s4_t o = {f2bf(d0 * rs * gv.x + bv.x), f2bf(d1 * rs * gv.y + bv.y),
            f2bf(d2 * rs * gv.z + bv.z), f2bf(d3 * rs * gv.w + bv.w)};
  *(s4_t*)(out + (long)row * 1024 + c) = o;
}

// ---------------------------------------------------------------------------
// GEMM (m97 structure): C[m][n] = sum_k A[m][k]*BT[n][k] (+bias) (+relu)
// A,BT bf16 in global, staged via global_load_lds width 16. 128x128 tile,
// BK=32, 256 threads = 4 waves (2x2), 4x4 MFMA frags each.
// Batch z: A += (z/batH)*sA1 + (z%batH)*sA2; BT += z*sBT; C += z*sC.
// qeSkip: skip output blocks never read by the causal QE gather.
// ---------------------------------------------------------------------------
template <int OUT_BF16, int RELU>
__global__ __launch_bounds__(256) void gemm_lds(
    const short* __restrict__ A, const short* __restrict__ BT,
    void* __restrict__ Cv, const float* __restrict__ biasp,
    int K, int lda, int ldb, int ldc,
    int batH, long sA1, long sA2, long sBT, long sC, int qeSkip) {
  __shared__ short As[4096];   // [128][32], unpadded (global_load_lds layout)
  __shared__ short Bs[4096];
  const int bm = blockIdx.y * 128, bn = blockIdx.x * 128;
  if (qeSkip && (bm + bn < 769)) return;
  const int tid = threadIdx.x;
  const int z = blockIdx.z;
  const int wave = tid >> 6, lane = tid & 63;
  const int quad = lane >> 4, l16 = lane & 15;
  const int wm = (wave >> 1) << 6, wn = (wave & 1) << 6;

  const short* Az = A + (long)(z / batH) * sA1 + (long)(z % batH) * sA2;
  const short* Bz = BT + (long)z * sBT;
  const int sr = wave * 32 + (lane >> 2);      // staging row (+16 for round 1)
  const int sc = (lane & 3) << 3;              // staging col (8 bf16 = 16 B)
  const short* Ag = Az + (long)(bm + sr) * lda + sc;
  const short* Bg = Bz + (long)(bn + sr) * ldb + sc;
  short* AsW = &As[wave * 1024];
  short* BsW = &Bs[wave * 1024];
  const long a16 = (long)16 * lda, b16 = (long)16 * ldb;

  f4v acc[4][4];
#pragma unroll
  for (int i = 0; i < 4; i++)
#pragma unroll
    for (int j = 0; j < 4; j++) {
      f4v zz = {0.f, 0.f, 0.f, 0.f};
      acc[i][j] = zz;
    }

  for (int k0 = 0; k0 < K; k0 += 32) {
    gld16(Ag + k0, AsW);
    gld16(Ag + k0 + a16, AsW + 512);
    gld16(Bg + k0, BsW);
    gld16(Bg + k0 + b16, BsW + 512);
    __syncthreads();
    s8_t af[4], bfr[4];
#pragma unroll
    for (int t = 0; t < 4; t++)
      af[t] = *(const s8_t*)&As[(wm + t * 16 + l16) * 32 + quad * 8];
#pragma unroll
    for (int t = 0; t < 4; t++)
      bfr[t] = *(const s8_t*)&Bs[(wn + t * 16 + l16) * 32 + quad * 8];
#pragma unroll
    for (int ti = 0; ti < 4; ti++)
#pragma unroll
      for (int tj = 0; tj < 4; tj++)
        acc[ti][tj] = mfma16(af[ti], bfr[tj], acc[ti][tj]);
    __syncthreads();
  }

  char* Cb = (char*)Cv + (long)z * sC * (OUT_BF16 ? 2 : 4);
#pragma unroll
  for (int ti = 0; ti < 4; ti++) {
#pragma unroll
    for (int tj = 0; tj < 4; tj++) {
      const int n = bn + wn + tj * 16 + l16;
      const float bval = biasp ? biasp[n] : 0.f;
#pragma unroll
      for (int r = 0; r < 4; r++) {
        const int m = bm + wm + ti * 16 + quad * 4 + r;
        float vv = acc[ti][tj][r] + bval;
        if (RELU) vv = fmaxf(vv, 0.f);
        if (OUT_BF16) ((short*)Cb)[(long)m * ldc + n] = f2bf(vv);
        else          ((float*)Cb)[(long)m * ldc + n] = vv;
      }
    }
  }
}

// ---------------------------------------------------------------------------
// Fused attention, online softmax + Music-Transformer rel-pos, bf16 I/O.
// grid (B*H, S/64); 256 threads = 4 waves, 16 q-rows each.
// Causal tile skip (exact: masked logits underflow to exactly 0); full sweep
// fallback for blocks containing rows whose entire prefix is pad-masked.
// ---------------------------------------------------------------------------
__global__ __launch_bounds__(256) void attn_kernel(
    const short* __restrict__ qkv, const short* __restrict__ QE,
    const int* __restrict__ xids, const int* __restrict__ fnp,
    short* __restrict__ outb) {
  __shared__ short Ks[64][72];      // [key][dim]
  __shared__ short Vt[64][72];      // [dim][key]
  __shared__ short Ps[4][16][72];   // per wave [row][key]
  __shared__ float kneg[64];

  const int bh = blockIdx.x, b = bh >> 4, hh = bh & 15;
  const int itile = 15 - (int)blockIdx.y;   // heavy blocks dispatch first
  const int tid = threadIdx.x;
  const int wave = tid >> 6, lane = tid & 63, quad = lane >> 4, l16 = lane & 15;
  const int i0 = itile * 64 + wave * 16;

  s8_t aq[2];
  {
    const short* qp = qkv + ((long)(b * 1024 + i0 + l16)) * 3072 + hh * 64 + quad * 8;
    aq[0] = *(const s8_t*)qp;
    aq[1] = *(const s8_t*)(qp + 32);
  }

  f4v o[4];
#pragma unroll
  for (int nt = 0; nt < 4; nt++) { f4v zz = {0.f, 0.f, 0.f, 0.f}; o[nt] = zz; }
  float m_run[4] = {-INFINITY, -INFINITY, -INFINITY, -INFINITY};
  float l_run[4] = {0.f, 0.f, 0.f, 0.f};

  const int jr = tid >> 2, c0 = (tid & 3) << 4;
  const short* kp0 = qkv + ((long)(b * 1024 + jr)) * 3072 + 1024 + hh * 64 + c0;
  const short* vp0 = kp0 + 1024;
  const int jEnd = (fnp[b] > itile * 64) ? 1024 : itile * 64 + 64;

  for (int j0 = 0; j0 < jEnd; j0 += 64) {
    const long joff = (long)j0 * 3072;
    *(s8_t*)&Ks[jr][c0] = *(const s8_t*)(kp0 + joff);
    *(s8_t*)&Ks[jr][c0 + 8] = *(const s8_t*)(kp0 + joff + 8);
    const s8_t v0 = *(const s8_t*)(vp0 + joff);
    const s8_t v1 = *(const s8_t*)(vp0 + joff + 8);
#pragma unroll
    for (int t = 0; t < 8; t++) {
      Vt[c0 + t][jr] = v0[t];
      Vt[c0 + 8 + t][jr] = v1[t];
    }
    if (tid < 64) kneg[tid] = (xids[b * 1024 + j0 + tid] == 0) ? -1e9f : 0.0f;
    __syncthreads();

    f4v sc[4];
#pragma unroll
    for (int nt = 0; nt < 4; nt++) {
      const s8_t k0f = *(const s8_t*)&Ks[nt * 16 + l16][quad * 8];
      const s8_t k1f = *(const s8_t*)&Ks[nt * 16 + l16][32 + quad * 8];
      f4v zz = {0.f, 0.f, 0.f, 0.f};
      zz = mfma16(aq[0], k0f, zz);
      zz = mfma16(aq[1], k1f, zz);
      sc[nt] = zz;
    }

    float p[4][4];
    const int irow = i0 + quad * 4;
#pragma unroll
    for (int nt = 0; nt < 4; nt++) {
      const int j = j0 + nt * 16 + l16;
#pragma unroll
      for (int r = 0; r < 4; r++) {
        const int i = irow + r;
        float s = sc[nt][r];
        if (j <= i) s += bf2f(QE[((long)bh * 1024 + i) * 1024 + (1023 - i + j)]);
        s *= 0.125f;
        s += (j > i) ? -1e9f : kneg[nt * 16 + l16];
        p[nt][r] = s;
      }
    }

    float alpha[4];
#pragma unroll
    for (int r = 0; r < 4; r++) {
      float mx = fmaxf(fmaxf(p[0][r], p[1][r]), fmaxf(p[2][r], p[3][r]));
      mx = fmaxf(mx, __shfl_xor(mx, 1));
      mx = fmaxf(mx, __shfl_xor(mx, 2));
      mx = fmaxf(mx, __shfl_xor(mx, 4));
      mx = fmaxf(mx, __shfl_xor(mx, 8));
      const float mnew = fmaxf(m_run[r], mx);
      alpha[r] = expf(m_run[r] - mnew);
      float ps = 0.f;
#pragma unroll
      for (int nt = 0; nt < 4; nt++) {
        p[nt][r] = expf(p[nt][r] - mnew);
        ps += p[nt][r];
      }
      ps += __shfl_xor(ps, 1);
      ps += __shfl_xor(ps, 2);
      ps += __shfl_xor(ps, 4);
      ps += __shfl_xor(ps, 8);
      l_run[r] = l_run[r] * alpha[r] + ps;
      m_run[r] = mnew;
    }

#pragma unroll
    for (int nt = 0; nt < 4; nt++) {
#pragma unroll
      for (int r = 0; r < 4; r++) {
        Ps[wave][quad * 4 + r][nt * 16 + l16] = f2bf(p[nt][r]);
        o[nt][r] *= alpha[r];
      }
    }

#pragma unroll
    for (int ks = 0; ks < 2; ks++) {
      const s8_t ap = *(const s8_t*)&Ps[wave][l16][ks * 32 + quad * 8];
#pragma unroll
      for (int nt = 0; nt < 4; nt++) {
        const s8_t vf = *(const s8_t*)&Vt[nt * 16 + l16][ks * 32 + quad * 8];
        o[nt] = mfma16(ap, vf, o[nt]);
      }
    }
    __syncthreads();
  }

#pragma unroll
  for (int nt = 0; nt < 4; nt++) {
#pragma unroll
    for (int r = 0; r < 4; r++) {
      const int i = i0 + quad * 4 + r;
      outb[((long)(b * 1024 + i)) * 1024 + hh * 64 + nt * 16 + l16] =
          f2bf(o[nt][r] / l_run[r]);
    }
  }
}

// ---------------------------------------------------------------------------
extern "C" void kernel_launch(void* const* d_in, const int* in_sizes, int n_in,
                              void* d_out, int out_size, void* d_ws, size_t ws_size,
                              hipStream_t stream) {
  const int*   x   = (const int*)d_in[0];
  const float* emb = (const float*)d_in[1];
  const float* Wq  = (const float*)d_in[2];
  const float* bq  = (const float*)d_in[3];
  const float* Wk  = (const float*)d_in[4];
  const float* bk  = (const float*)d_in[5];
  const float* Wv  = (const float*)d_in[6];
  const float* bv  = (const float*)d_in[7];
  const float* Wo  = (const float*)d_in[8];
  const float* bo  = (const float*)d_in[9];
  const float* W1  = (const float*)d_in[10];
  const float* b1  = (const float*)d_in[11];
  const float* W2  = (const float*)d_in[12];
  const float* b2  = (const float*)d_in[13];
  const float* g1  = (const float*)d_in[14];
  const float* be1 = (const float*)d_in[15];
  const float* g2  = (const float*)d_in[16];
  const float* be2 = (const float*)d_in[17];
  const float* E   = (const float*)d_in[18];
  const float* Wf  = (const float*)d_in[19];
  const float* bfv = (const float*)d_in[20];

  char* p = (char*)d_ws;
  auto alloc = [&](size_t bytes) {
    char* r = p;
    p += (bytes + 255) & ~(size_t)255;
    return r;
  };
  short* h    = (short*)alloc(2048ull * 1024 * 2);
  short* qkv  = (short*)alloc(2048ull * 3072 * 2);
  short* attn = (short*)alloc(2048ull * 1024 * 2);
  short* tmp  = (short*)alloc(2048ull * 1024 * 2);
  short* mid  = (short*)alloc(2048ull * 512 * 2);
  short* QEb  = (short*)alloc(32ull * 1024 * 1024 * 2);
  short* qkvT = (short*)alloc(6ull * 3072 * 1024 * 2);
  short* WoT  = (short*)alloc(6ull * 1024 * 1024 * 2);
  short* W1T  = (short*)alloc(6ull * 512 * 1024 * 2);
  short* W2T  = (short*)alloc(6ull * 1024 * 512 * 2);
  short* WfT  = (short*)alloc(256ull * 1024 * 2);
  short* Ebf  = (short*)alloc(6ull * 1024 * 64 * 2);
  float* qkvB = (float*)alloc(6ull * 3072 * 4);
  int*   fnp  = (int*)alloc(2 * sizeof(int));

  const dim3 tb(32, 8);
  // weight prep
  transpose_bf16<<<dim3(32, 32, 6), tb, 0, stream>>>(Wq, qkvT, 1024, 1024, 3072 * 1024, 0);
  transpose_bf16<<<dim3(32, 32, 6), tb, 0, stream>>>(Wk, qkvT, 1024, 1024, 3072 * 1024, 1024);
  transpose_bf16<<<dim3(32, 32, 6), tb, 0, stream>>>(Wv, qkvT, 1024, 1024, 3072 * 1024, 2048);
  transpose_bf16<<<dim3(32, 32, 6), tb, 0, stream>>>(Wo, WoT, 1024, 1024, 1024 * 1024, 0);
  transpose_bf16<<<dim3(16, 32, 6), tb, 0, stream>>>(W1, W1T, 1024, 512, 512 * 1024, 0);
  transpose_bf16<<<dim3(32, 16, 6), tb, 0, stream>>>(W2, W2T, 512, 1024, 1024 * 512, 0);
  transpose_bf16<<<dim3(8, 32, 1), tb, 0, stream>>>(Wf, WfT, 1024, 256, 256 * 1024, 0);
  cvt_bf16<<<384, 256, 0, stream>>>(E, Ebf);
  qkv_bias_kernel<<<72, 256, 0, stream>>>(bq, bk, bv, qkvB);
  fnp_kernel<<<2, 64, 0, stream>>>(x, fnp);
  embed_kernel<<<2048, 256, 0, stream>>>(x, emb, h);

  for (int l = 0; l < 6; l++) {
    const long wOff = (long)l * 1024 * 1024;
    const long w12Off = (long)l * 512 * 1024;
    // fused QKV projection: [2048,1024] x [3072,1024]^T -> [2048,3072]
    gemm_lds<1, 0><<<dim3(24, 16, 1), 256, 0, stream>>>(
        h, qkvT + (long)l * 3072 * 1024, qkv, qkvB + l * 3072,
        1024, 1024, 1024, 3072, 1, 0, 0, 0, 0, 0);
    // QE[bh][i][m] = q[b,i,hh*64+:] . E[l][m][:], causal blocks only
    gemm_lds<1, 0><<<dim3(8, 8, 32), 256, 0, stream>>>(
        qkv, Ebf + (long)l * 1024 * 64, QEb, nullptr,
        64, 3072, 64, 1024, 16, (long)1024 * 3072, 64, 0, (long)1024 * 1024, 1);
    // fused attention
    attn_kernel<<<dim3(32, 16), 256, 0, stream>>>(qkv, QEb, x, fnp, attn);
    // output projection + LN
    gemm_lds<1, 0><<<dim3(8, 16, 1), 256, 0, stream>>>(
        attn, WoT + wOff, tmp, bo + l * 1024, 1024, 1024, 1024, 1024, 1, 0, 0, 0, 0, 0);
    ln_kernel<<<2048, 256, 0, stream>>>(tmp, tmp, g1 + l * 1024, be1 + l * 1024);
    // FFN
    gemm_lds<1, 1><<<dim3(4, 16, 1), 256, 0, stream>>>(
        tmp, W1T + w12Off, mid, b1 + l * 512, 1024, 1024, 1024, 512, 1, 0, 0, 0, 0, 0);
    gemm_lds<1, 0><<<dim3(8, 16, 1), 256, 0, stream>>>(
        mid, W2T + w12Off, h, b2 + l * 1024, 512, 512, 512, 1024, 1, 0, 0, 0, 0, 0);
    ln_kernel<<<2048, 256, 0, stream>>>(h, h, g2 + l * 1024, be2 + l * 1024);
  }
  // final projection -> d_out (f32)
  gemm_lds<0, 0><<<dim3(2, 16, 1), 256, 0, stream>>>(
      h, WfT, (float*)d_out, bfv, 1024, 1024, 1024, 256, 1, 0, 0, 0, 0, 0);
}

// Round 3
// 1211.506 us; speedup vs baseline: 2.0836x; 1.4038x over previous
//
#include <hip/hip_runtime.h>
#include <hip/hip_bf16.h>

// ---------------------------------------------------------------------------
// ArrowTransformer forward: B=2, S=1024, D=1024, H=16, HD=64, L=6, V=256
// Round 2: split-j flash-decoding attention (1280 blocks + combine + rare
// pad-fallback kernel), generic GEMM tiling (64x64 for grid-starved GEMMs).
// ---------------------------------------------------------------------------

typedef __attribute__((ext_vector_type(8))) short  s8_t;
typedef __attribute__((ext_vector_type(4))) short  s4_t;
typedef __attribute__((ext_vector_type(8))) __bf16 bf8_t;
typedef __attribute__((ext_vector_type(4))) float  f4v;

static __device__ __forceinline__ short f2bf(float f) {
  union { float f; unsigned u; } a; a.f = f;
  unsigned u = a.u;
  u += 0x7fffu + ((u >> 16) & 1u);
  return (short)(u >> 16);
}
static __device__ __forceinline__ float bf2f(short s) {
  union { float f; unsigned u; } a;
  a.u = ((unsigned)(unsigned short)s) << 16;
  return a.f;
}
static __device__ __forceinline__ f4v mfma16(s8_t a, s8_t b, f4v c) {
  return __builtin_amdgcn_mfma_f32_16x16x32_bf16(
      __builtin_bit_cast(bf8_t, a), __builtin_bit_cast(bf8_t, b), c, 0, 0, 0);
}
static __device__ __forceinline__ void gld16(const short* g, short* l) {
  __builtin_amdgcn_global_load_lds(
      (const __attribute__((address_space(1))) void*)g,
      (__attribute__((address_space(3))) void*)l, 16, 0, 0);
}

// chunk table: heavy q-tiles first. nc(itile) = itile/4 + 1.
static __device__ const int IT_TAB[40] = {
  15,15,15,15, 14,14,14,14, 13,13,13,13, 12,12,12,12,
  11,11,11, 10,10,10, 9,9,9, 8,8,8,
  7,7, 6,6, 5,5, 4,4, 3, 2, 1, 0};
static __device__ const int CW_TAB[40] = {
  0,1,2,3, 0,1,2,3, 0,1,2,3, 0,1,2,3,
  0,1,2, 0,1,2, 0,1,2, 0,1,2,
  0,1, 0,1, 0,1, 0,1, 0, 0, 0, 0};

// ---------------------------------------------------------------------------
__global__ void transpose_bf16(const float* __restrict__ in, short* __restrict__ out,
                               int R, int C, long outBS, int outRowOff) {
  __shared__ float tile[32][33];
  const long zi = (long)blockIdx.z * R * C;
  out += (long)blockIdx.z * outBS + (long)outRowOff * R;
  const int c0 = blockIdx.x * 32, r0 = blockIdx.y * 32;
  const int tx = threadIdx.x, ty = threadIdx.y;
#pragma unroll
  for (int i = 0; i < 4; i++)
    tile[ty + i * 8][tx] = in[zi + (long)(r0 + ty + i * 8) * C + c0 + tx];
  __syncthreads();
#pragma unroll
  for (int i = 0; i < 4; i++)
    out[(long)(c0 + ty + i * 8) * R + r0 + tx] = f2bf(tile[tx][ty + i * 8]);
}

__global__ __launch_bounds__(256) void cvt_bf16(const float* __restrict__ in,
                                                short* __restrict__ out) {
  const long i = ((long)blockIdx.x * 256 + threadIdx.x) * 4;
  const float4 t = *(const float4*)(in + i);
  s4_t o = {f2bf(t.x), f2bf(t.y), f2bf(t.z), f2bf(t.w)};
  *(s4_t*)(out + i) = o;
}

__global__ void qkv_bias_kernel(const float* __restrict__ bq, const float* __restrict__ bk,
                                const float* __restrict__ bv, float* __restrict__ out) {
  const int idx = blockIdx.x * 256 + threadIdx.x;
  const int l = idx / 3072, n = idx % 3072;
  float v = (n < 1024) ? bq[l * 1024 + n]
          : (n < 2048) ? bk[l * 1024 + n - 1024]
                       : bv[l * 1024 + n - 2048];
  out[idx] = v;
}

__global__ void fnp_kernel(const int* __restrict__ x, int* __restrict__ fnp) {
  const int b = blockIdx.x, lane = threadIdx.x;
  int first = 1024;
  for (int j0 = 0; j0 < 1024; j0 += 64) {
    unsigned long long m = __ballot(x[b * 1024 + j0 + lane] != 0);
    if (m) { first = j0 + __ffsll(m) - 1; break; }
  }
  if (lane == 0) fnp[b] = first;
}

__global__ __launch_bounds__(256) void embed_kernel(const int* __restrict__ x,
                                                    const float* __restrict__ emb,
                                                    short* __restrict__ h) {
  const int row = blockIdx.x;
  const int s = row & 1023;
  const int xv = x[row];
  const int c = threadIdx.x << 2;
  const float4 e = *(const float4*)(emb + (long)xv * 1024 + c);
  const float ev[4] = {e.x, e.y, e.z, e.w};
  s4_t o;
#pragma unroll
  for (int i = 0; i < 4; i++) {
    const int d = c + i;
    const float par = (float)(d & 1);
    const float rate = expf(-9.210340371976184f * (float)d / 1024.0f) *
                       expf(9.210340371976184f * par / 1024.0f);
    const float pe = sinf((float)s * rate + 1.5707963267948966f * par);
    o[i] = f2bf(ev[i] * 32.0f + pe);
  }
  *(s4_t*)(h + (long)row * 1024 + c) = o;
}

__global__ __launch_bounds__(256) void ln_kernel(const short* __restrict__ in,
                                                 short* __restrict__ out,
                                                 const float* __restrict__ g,
                                                 const float* __restrict__ be) {
  __shared__ float red[4];
  __shared__ float red2[4];
  const int row = blockIdx.x;
  const int tid = threadIdx.x;
  const int c = tid << 2;
  const s4_t xv = *(const s4_t*)(in + (long)row * 1024 + c);
  const float x0 = bf2f(xv[0]), x1 = bf2f(xv[1]), x2 = bf2f(xv[2]), x3 = bf2f(xv[3]);
  float s = x0 + x1 + x2 + x3;
#pragma unroll
  for (int off = 1; off < 64; off <<= 1) s += __shfl_xor(s, off);
  const int wave = tid >> 6, lane = tid & 63;
  if (lane == 0) red[wave] = s;
  __syncthreads();
  const float mu = (red[0] + red[1] + red[2] + red[3]) * (1.0f / 1024.0f);
  const float d0 = x0 - mu, d1 = x1 - mu, d2 = x2 - mu, d3 = x3 - mu;
  float q = d0 * d0 + d1 * d1 + d2 * d2 + d3 * d3;
#pragma unroll
  for (int off = 1; off < 64; off <<= 1) q += __shfl_xor(q, off);
  if (lane == 0) red2[wave] = q;
  __syncthreads();
  const float var = (red2[0] + red2[1] + red2[2] + red2[3]) * (1.0f / 1024.0f);
  const float rs = rsqrtf(var + 1e-6f);
  const float4 gv = *(const float4*)(g + c);
  const float4 bv = *(const float4*)(be + c);
  s4_t o = {f2bf(d0 * rs * gv.x + bv.x), f2bf(d1 * rs * gv.y + bv.y),
            f2bf(d2 * rs * gv.z + bv.z), f2bf(d3 * rs * gv.w + bv.w)};
  *(s4_t*)(out + (long)row * 1024 + c) = o;
}

// ---------------------------------------------------------------------------
// Generic MFMA GEMM: C[m][n] = sum_k A[m][k]*BT[n][k] (+bias) (+relu)
// BM x BN tile, BK=32, 256 threads = 4 waves arranged WR x WC.
// A,BT bf16, staged via global_load_lds width 16.
// ---------------------------------------------------------------------------
template <int BM, int BN, int WR, int WC, int OUT_BF16, int RELU>
__global__ __launch_bounds__(256) void gemm_lds(
    const short* __restrict__ A, const short* __restrict__ BT,
    void* __restrict__ Cv, const float* __restrict__ biasp,
    int K, int lda, int ldb, int ldc,
    int batH, long sA1, long sA2, long sBT, long sC, int qeSkip) {
  constexpr int AR = BM / 64, BR = BN / 64;
  constexpr int FI = BM / WR / 16, FJ = BN / WC / 16;
  __shared__ short As[BM * 32];
  __shared__ short Bs[BN * 32];
  const int bm = blockIdx.y * BM, bn = blockIdx.x * BN;
  if (qeSkip && (bm + bn + BM + BN - 2 < 1023)) return;
  const int tid = threadIdx.x;
  const int z = blockIdx.z;
  const int wave = tid >> 6, lane = tid & 63;
  const int quad = lane >> 4, l16 = lane & 15;
  const int wr = wave / WC, wc = wave % WC;
  const int wm = wr * (BM / WR), wn = wc * (BN / WC);

  const short* Az = A + (long)(z / batH) * sA1 + (long)(z % batH) * sA2;
  const short* Bz = BT + (long)z * sBT;
  const short* Ag = Az + (long)(bm + wave * 16 + (lane >> 2)) * lda + ((lane & 3) << 3);
  const short* Bg = Bz + (long)(bn + wave * 16 + (lane >> 2)) * ldb + ((lane & 3) << 3);

  f4v acc[FI][FJ];
#pragma unroll
  for (int i = 0; i < FI; i++)
#pragma unroll
    for (int j = 0; j < FJ; j++) {
      f4v zz = {0.f, 0.f, 0.f, 0.f};
      acc[i][j] = zz;
    }

  for (int k0 = 0; k0 < K; k0 += 32) {
#pragma unroll
    for (int r = 0; r < AR; r++)
      gld16(Ag + (long)r * 64 * lda + k0, As + r * 2048 + wave * 512);
#pragma unroll
    for (int r = 0; r < BR; r++)
      gld16(Bg + (long)r * 64 * ldb + k0, Bs + r * 2048 + wave * 512);
    __syncthreads();
    s8_t af[FI], bfr[FJ];
#pragma unroll
    for (int t = 0; t < FI; t++)
      af[t] = *(const s8_t*)&As[(wm + t * 16 + l16) * 32 + quad * 8];
#pragma unroll
    for (int t = 0; t < FJ; t++)
      bfr[t] = *(const s8_t*)&Bs[(wn + t * 16 + l16) * 32 + quad * 8];
#pragma unroll
    for (int ti = 0; ti < FI; ti++)
#pragma unroll
      for (int tj = 0; tj < FJ; tj++)
        acc[ti][tj] = mfma16(af[ti], bfr[tj], acc[ti][tj]);
    __syncthreads();
  }

  char* Cb = (char*)Cv + (long)z * sC * (OUT_BF16 ? 2 : 4);
#pragma unroll
  for (int ti = 0; ti < FI; ti++) {
#pragma unroll
    for (int tj = 0; tj < FJ; tj++) {
      const int n = bn + wn + tj * 16 + l16;
      const float bval = biasp ? biasp[n] : 0.f;
#pragma unroll
      for (int r = 0; r < 4; r++) {
        const int m = bm + wm + ti * 16 + quad * 4 + r;
        float vv = acc[ti][tj][r] + bval;
        if (RELU) vv = fmaxf(vv, 0.f);
        if (OUT_BF16) ((short*)Cb)[(long)m * ldc + n] = f2bf(vv);
        else          ((float*)Cb)[(long)m * ldc + n] = vv;
      }
    }
  }
}

// ---------------------------------------------------------------------------
// Split-j attention main: grid (B*H=32, 40 chunks). Block = (bh, itile, cw),
// processes key-tiles [4*cw, min(4*cw+3, itile)]. Writes partial (m,l,O-f32).
// ---------------------------------------------------------------------------
__global__ __launch_bounds__(256) void attn_main(
    const short* __restrict__ qkv, const short* __restrict__ QE,
    const int* __restrict__ xids,
    float* __restrict__ PO, float* __restrict__ PM, float* __restrict__ PL) {
  __shared__ short Ks[64][72];
  __shared__ short Vt[64][72];
  __shared__ short Ps[4][16][72];
  __shared__ float kneg[64];

  const int bh = blockIdx.x, b = bh >> 4, hh = bh & 15;
  const int itile = IT_TAB[blockIdx.y], cw = CW_TAB[blockIdx.y];
  const int tid = threadIdx.x;
  const int wave = tid >> 6, lane = tid & 63, quad = lane >> 4, l16 = lane & 15;
  const int i0 = itile * 64 + wave * 16;

  s8_t aq[2];
  {
    const short* qp = qkv + ((long)(b * 1024 + i0 + l16)) * 3072 + hh * 64 + quad * 8;
    aq[0] = *(const s8_t*)qp;
    aq[1] = *(const s8_t*)(qp + 32);
  }

  f4v o[4];
#pragma unroll
  for (int nt = 0; nt < 4; nt++) { f4v zz = {0.f, 0.f, 0.f, 0.f}; o[nt] = zz; }
  float m_run[4] = {-INFINITY, -INFINITY, -INFINITY, -INFINITY};
  float l_run[4] = {0.f, 0.f, 0.f, 0.f};

  const int jr = tid >> 2, c0 = (tid & 3) << 4;
  const short* kp0 = qkv + ((long)(b * 1024 + jr)) * 3072 + 1024 + hh * 64 + c0;
  const short* vp0 = kp0 + 1024;

  const int jBeg = cw * 4 * 64;
  const int jEnd = min(cw * 4 + 4, itile + 1) * 64;

  for (int j0 = jBeg; j0 < jEnd; j0 += 64) {
    const long joff = (long)j0 * 3072;
    *(s8_t*)&Ks[jr][c0] = *(const s8_t*)(kp0 + joff);
    *(s8_t*)&Ks[jr][c0 + 8] = *(const s8_t*)(kp0 + joff + 8);
    const s8_t v0 = *(const s8_t*)(vp0 + joff);
    const s8_t v1 = *(const s8_t*)(vp0 + joff + 8);
#pragma unroll
    for (int t = 0; t < 8; t++) {
      Vt[c0 + t][jr] = v0[t];
      Vt[c0 + 8 + t][jr] = v1[t];
    }
    if (tid < 64) kneg[tid] = (xids[b * 1024 + j0 + tid] == 0) ? -1e9f : 0.0f;
    __syncthreads();

    f4v sc[4];
#pragma unroll
    for (int nt = 0; nt < 4; nt++) {
      const s8_t k0f = *(const s8_t*)&Ks[nt * 16 + l16][quad * 8];
      const s8_t k1f = *(const s8_t*)&Ks[nt * 16 + l16][32 + quad * 8];
      f4v zz = {0.f, 0.f, 0.f, 0.f};
      zz = mfma16(aq[0], k0f, zz);
      zz = mfma16(aq[1], k1f, zz);
      sc[nt] = zz;
    }

    float p[4][4];
    const int irow = i0 + quad * 4;
#pragma unroll
    for (int nt = 0; nt < 4; nt++) {
      const int j = j0 + nt * 16 + l16;
#pragma unroll
      for (int r = 0; r < 4; r++) {
        const int i = irow + r;
        float s = sc[nt][r];
        if (j <= i) s += bf2f(QE[((long)bh * 1024 + i) * 1024 + (1023 - i + j)]);
        s *= 0.125f;
        s += (j > i) ? -1e9f : kneg[nt * 16 + l16];
        p[nt][r] = s;
      }
    }

    float alpha[4];
#pragma unroll
    for (int r = 0; r < 4; r++) {
      float mx = fmaxf(fmaxf(p[0][r], p[1][r]), fmaxf(p[2][r], p[3][r]));
      mx = fmaxf(mx, __shfl_xor(mx, 1));
      mx = fmaxf(mx, __shfl_xor(mx, 2));
      mx = fmaxf(mx, __shfl_xor(mx, 4));
      mx = fmaxf(mx, __shfl_xor(mx, 8));
      const float mnew = fmaxf(m_run[r], mx);
      alpha[r] = expf(m_run[r] - mnew);
      float ps = 0.f;
#pragma unroll
      for (int nt = 0; nt < 4; nt++) {
        p[nt][r] = expf(p[nt][r] - mnew);
        ps += p[nt][r];
      }
      ps += __shfl_xor(ps, 1);
      ps += __shfl_xor(ps, 2);
      ps += __shfl_xor(ps, 4);
      ps += __shfl_xor(ps, 8);
      l_run[r] = l_run[r] * alpha[r] + ps;
      m_run[r] = mnew;
    }

#pragma unroll
    for (int nt = 0; nt < 4; nt++) {
#pragma unroll
      for (int r = 0; r < 4; r++) {
        Ps[wave][quad * 4 + r][nt * 16 + l16] = f2bf(p[nt][r]);
        o[nt][r] *= alpha[r];
      }
    }

#pragma unroll
    for (int ks = 0; ks < 2; ks++) {
      const s8_t ap = *(const s8_t*)&Ps[wave][l16][ks * 32 + quad * 8];
#pragma unroll
      for (int nt = 0; nt < 4; nt++) {
        const s8_t vf = *(const s8_t*)&Vt[nt * 16 + l16][ks * 32 + quad * 8];
        o[nt] = mfma16(ap, vf, o[nt]);
      }
    }
    __syncthreads();
  }

  const long part = (long)(bh * 16 + itile) * 4 + cw;
  float* po = PO + part * 4096;
#pragma unroll
  for (int nt = 0; nt < 4; nt++) {
#pragma unroll
    for (int r = 0; r < 4; r++) {
      const int row = wave * 16 + quad * 4 + r;
      po[row * 64 + nt * 16 + l16] = o[nt][r];
    }
  }
  if (l16 == 0) {
#pragma unroll
    for (int r = 0; r < 4; r++) {
      const int row = wave * 16 + quad * 4 + r;
      PM[part * 64 + row] = m_run[r];
      PL[part * 64 + row] = l_run[r];
    }
  }
}

// combine partial chunks -> output. grid 512 blocks (bh*16+itile), 256 thr.
__global__ __launch_bounds__(256) void attn_combine(
    const float* __restrict__ PO, const float* __restrict__ PM,
    const float* __restrict__ PL, short* __restrict__ outb) {
  const int id = blockIdx.x;
  const int bh = id >> 4, itile = id & 15;
  const int b = bh >> 4, hh = bh & 15;
  const int nc = (itile >> 2) + 1;
  const int row = threadIdx.x >> 2, seg = (threadIdx.x & 3) << 4;
  const long base = (long)id * 4;

  float mv[4];
  float M = -INFINITY;
  for (int c = 0; c < nc; c++) {
    mv[c] = PM[(base + c) * 64 + row];
    M = fmaxf(M, mv[c]);
  }
  f4v acc[4];
#pragma unroll
  for (int t = 0; t < 4; t++) { f4v zz = {0.f, 0.f, 0.f, 0.f}; acc[t] = zz; }
  float l = 0.f;
  for (int c = 0; c < nc; c++) {
    const float w = expf(mv[c] - M);
    l += w * PL[(base + c) * 64 + row];
    const float* po = PO + (base + c) * 4096 + row * 64 + seg;
#pragma unroll
    for (int t = 0; t < 4; t++) {
      const f4v v = *(const f4v*)(po + t * 4);
      acc[t] += w * v;
    }
  }
  const float inv = 1.0f / l;
  const int i = itile * 64 + row;
  short* op = outb + ((long)(b * 1024 + i)) * 1024 + hh * 64 + seg;
#pragma unroll
  for (int t = 0; t < 4; t++) {
    s4_t o = {f2bf(acc[t][0] * inv), f2bf(acc[t][1] * inv),
              f2bf(acc[t][2] * inv), f2bf(acc[t][3] * inv)};
    *(s4_t*)(op + t * 4) = o;
  }
}

// ---------------------------------------------------------------------------
// Pad fallback: rows i < fnp[b] are fully masked; reference softmax reduces to
// UNMASKED attention over all keys (the -1e9 is a uniform shift). Rare path;
// early-exits when fnp[b]==0. Overwrites affected output rows.
// ---------------------------------------------------------------------------
__global__ __launch_bounds__(256) void attn_fallback(
    const short* __restrict__ qkv, const short* __restrict__ QE,
    const int* __restrict__ fnp, short* __restrict__ outb) {
  const int bh = blockIdx.x, b = bh >> 4, hh = bh & 15;
  const int itile = blockIdx.y;
  const int fb = fnp[b];
  if (fb <= itile * 64) return;

  __shared__ short Ks[64][72];
  __shared__ short Vt[64][72];
  __shared__ short Ps[4][16][72];

  const int tid = threadIdx.x;
  const int wave = tid >> 6, lane = tid & 63, quad = lane >> 4, l16 = lane & 15;
  const int i0 = itile * 64 + wave * 16;

  s8_t aq[2];
  {
    const short* qp = qkv + ((long)(b * 1024 + i0 + l16)) * 3072 + hh * 64 + quad * 8;
    aq[0] = *(const s8_t*)qp;
    aq[1] = *(const s8_t*)(qp + 32);
  }
  f4v o[4];
#pragma unroll
  for (int nt = 0; nt < 4; nt++) { f4v zz = {0.f, 0.f, 0.f, 0.f}; o[nt] = zz; }
  float m_run[4] = {-INFINITY, -INFINITY, -INFINITY, -INFINITY};
  float l_run[4] = {0.f, 0.f, 0.f, 0.f};

  const int jr = tid >> 2, c0 = (tid & 3) << 4;
  const short* kp0 = qkv + ((long)(b * 1024 + jr)) * 3072 + 1024 + hh * 64 + c0;
  const short* vp0 = kp0 + 1024;

  for (int j0 = 0; j0 < 1024; j0 += 64) {
    const long joff = (long)j0 * 3072;
    *(s8_t*)&Ks[jr][c0] = *(const s8_t*)(kp0 + joff);
    *(s8_t*)&Ks[jr][c0 + 8] = *(const s8_t*)(kp0 + joff + 8);
    const s8_t v0 = *(const s8_t*)(vp0 + joff);
    const s8_t v1 = *(const s8_t*)(vp0 + joff + 8);
#pragma unroll
    for (int t = 0; t < 8; t++) {
      Vt[c0 + t][jr] = v0[t];
      Vt[c0 + 8 + t][jr] = v1[t];
    }
    __syncthreads();

    f4v sc[4];
#pragma unroll
    for (int nt = 0; nt < 4; nt++) {
      const s8_t k0f = *(const s8_t*)&Ks[nt * 16 + l16][quad * 8];
      const s8_t k1f = *(const s8_t*)&Ks[nt * 16 + l16][32 + quad * 8];
      f4v zz = {0.f, 0.f, 0.f, 0.f};
      zz = mfma16(aq[0], k0f, zz);
      zz = mfma16(aq[1], k1f, zz);
      sc[nt] = zz;
    }
    float p[4][4];
    const int irow = i0 + quad * 4;
#pragma unroll
    for (int nt = 0; nt < 4; nt++) {
      const int j = j0 + nt * 16 + l16;
#pragma unroll
      for (int r = 0; r < 4; r++) {
        const int i = irow + r;
        float s = sc[nt][r];
        if (j <= i) s += bf2f(QE[((long)bh * 1024 + i) * 1024 + (1023 - i + j)]);
        p[nt][r] = s * 0.125f;
      }
    }
    float alpha[4];
#pragma unroll
    for (int r = 0; r < 4; r++) {
      float mx = fmaxf(fmaxf(p[0][r], p[1][r]), fmaxf(p[2][r], p[3][r]));
      mx = fmaxf(mx, __shfl_xor(mx, 1));
      mx = fmaxf(mx, __shfl_xor(mx, 2));
      mx = fmaxf(mx, __shfl_xor(mx, 4));
      mx = fmaxf(mx, __shfl_xor(mx, 8));
      const float mnew = fmaxf(m_run[r], mx);
      alpha[r] = expf(m_run[r] - mnew);
      float ps = 0.f;
#pragma unroll
      for (int nt = 0; nt < 4; nt++) {
        p[nt][r] = expf(p[nt][r] - mnew);
        ps += p[nt][r];
      }
      ps += __shfl_xor(ps, 1);
      ps += __shfl_xor(ps, 2);
      ps += __shfl_xor(ps, 4);
      ps += __shfl_xor(ps, 8);
      l_run[r] = l_run[r] * alpha[r] + ps;
      m_run[r] = mnew;
    }
#pragma unroll
    for (int nt = 0; nt < 4; nt++) {
#pragma unroll
      for (int r = 0; r < 4; r++) {
        Ps[wave][quad * 4 + r][nt * 16 + l16] = f2bf(p[nt][r]);
        o[nt][r] *= alpha[r];
      }
    }
#pragma unroll
    for (int ks = 0; ks < 2; ks++) {
      const s8_t ap = *(const s8_t*)&Ps[wave][l16][ks * 32 + quad * 8];
#pragma unroll
      for (int nt = 0; nt < 4; nt++) {
        const s8_t vf = *(const s8_t*)&Vt[nt * 16 + l16][ks * 32 + quad * 8];
        o[nt] = mfma16(ap, vf, o[nt]);
      }
    }
    __syncthreads();
  }

#pragma unroll
  for (int nt = 0; nt < 4; nt++) {
#pragma unroll
    for (int r = 0; r < 4; r++) {
      const int i = i0 + quad * 4 + r;
      if (i < fb)
        outb[((long)(b * 1024 + i)) * 1024 + hh * 64 + nt * 16 + l16] =
            f2bf(o[nt][r] / l_run[r]);
    }
  }
}

// ---------------------------------------------------------------------------
extern "C" void kernel_launch(void* const* d_in, const int* in_sizes, int n_in,
                              void* d_out, int out_size, void* d_ws, size_t ws_size,
                              hipStream_t stream) {
  const int*   x   = (const int*)d_in[0];
  const float* emb = (const float*)d_in[1];
  const float* Wq  = (const float*)d_in[2];
  const float* bq  = (const float*)d_in[3];
  const float* Wk  = (const float*)d_in[4];
  const float* bk  = (const float*)d_in[5];
  const float* Wv  = (const float*)d_in[6];
  const float* bv  = (const float*)d_in[7];
  const float* Wo  = (const float*)d_in[8];
  const float* bo  = (const float*)d_in[9];
  const float* W1  = (const float*)d_in[10];
  const float* b1  = (const float*)d_in[11];
  const float* W2  = (const float*)d_in[12];
  const float* b2  = (const float*)d_in[13];
  const float* g1  = (const float*)d_in[14];
  const float* be1 = (const float*)d_in[15];
  const float* g2  = (const float*)d_in[16];
  const float* be2 = (const float*)d_in[17];
  const float* E   = (const float*)d_in[18];
  const float* Wf  = (const float*)d_in[19];
  const float* bfv = (const float*)d_in[20];

  char* p = (char*)d_ws;
  auto alloc = [&](size_t bytes) {
    char* r = p;
    p += (bytes + 255) & ~(size_t)255;
    return r;
  };
  short* h    = (short*)alloc(2048ull * 1024 * 2);
  short* qkv  = (short*)alloc(2048ull * 3072 * 2);
  short* attn = (short*)alloc(2048ull * 1024 * 2);
  short* tmp  = (short*)alloc(2048ull * 1024 * 2);
  short* mid  = (short*)alloc(2048ull * 512 * 2);
  short* QEb  = (short*)alloc(32ull * 1024 * 1024 * 2);
  short* qkvT = (short*)alloc(6ull * 3072 * 1024 * 2);
  short* WoT  = (short*)alloc(6ull * 1024 * 1024 * 2);
  short* W1T  = (short*)alloc(6ull * 512 * 1024 * 2);
  short* W2T  = (short*)alloc(6ull * 1024 * 512 * 2);
  short* WfT  = (short*)alloc(256ull * 1024 * 2);
  short* Ebf  = (short*)alloc(6ull * 1024 * 64 * 2);
  float* qkvB = (float*)alloc(6ull * 3072 * 4);
  int*   fnp  = (int*)alloc(256);
  float* PO   = (float*)alloc(2048ull * 4096 * 4);   // 512 tiles x 4 chunks x 64x64
  float* PM   = (float*)alloc(2048ull * 64 * 4);
  float* PL   = (float*)alloc(2048ull * 64 * 4);

  const dim3 tb(32, 8);
  transpose_bf16<<<dim3(32, 32, 6), tb, 0, stream>>>(Wq, qkvT, 1024, 1024, 3072 * 1024, 0);
  transpose_bf16<<<dim3(32, 32, 6), tb, 0, stream>>>(Wk, qkvT, 1024, 1024, 3072 * 1024, 1024);
  transpose_bf16<<<dim3(32, 32, 6), tb, 0, stream>>>(Wv, qkvT, 1024, 1024, 3072 * 1024, 2048);
  transpose_bf16<<<dim3(32, 32, 6), tb, 0, stream>>>(Wo, WoT, 1024, 1024, 1024 * 1024, 0);
  transpose_bf16<<<dim3(16, 32, 6), tb, 0, stream>>>(W1, W1T, 1024, 512, 512 * 1024, 0);
  transpose_bf16<<<dim3(32, 16, 6), tb, 0, stream>>>(W2, W2T, 512, 1024, 1024 * 512, 0);
  transpose_bf16<<<dim3(8, 32, 1), tb, 0, stream>>>(Wf, WfT, 1024, 256, 256 * 1024, 0);
  cvt_bf16<<<384, 256, 0, stream>>>(E, Ebf);
  qkv_bias_kernel<<<72, 256, 0, stream>>>(bq, bk, bv, qkvB);
  fnp_kernel<<<2, 64, 0, stream>>>(x, fnp);
  embed_kernel<<<2048, 256, 0, stream>>>(x, emb, h);

  for (int l = 0; l < 6; l++) {
    const long wOff = (long)l * 1024 * 1024;
    const long w12Off = (long)l * 512 * 1024;
    gemm_lds<128, 128, 2, 2, 1, 0><<<dim3(24, 16, 1), 256, 0, stream>>>(
        h, qkvT + (long)l * 3072 * 1024, qkv, qkvB + l * 3072,
        1024, 1024, 1024, 3072, 1, 0, 0, 0, 0, 0);
    gemm_lds<128, 128, 2, 2, 1, 0><<<dim3(8, 8, 32), 256, 0, stream>>>(
        qkv, Ebf + (long)l * 1024 * 64, QEb, nullptr,
        64, 3072, 64, 1024, 16, (long)1024 * 3072, 64, 0, (long)1024 * 1024, 1);
    attn_main<<<dim3(32, 40), 256, 0, stream>>>(qkv, QEb, x, PO, PM, PL);
    attn_combine<<<512, 256, 0, stream>>>(PO, PM, PL, attn);
    attn_fallback<<<dim3(32, 16), 256, 0, stream>>>(qkv, QEb, fnp, attn);
    gemm_lds<64, 64, 2, 2, 1, 0><<<dim3(16, 32, 1), 256, 0, stream>>>(
        attn, WoT + wOff, tmp, bo + l * 1024, 1024, 1024, 1024, 1024, 1, 0, 0, 0, 0, 0);
    ln_kernel<<<2048, 256, 0, stream>>>(tmp, tmp, g1 + l * 1024, be1 + l * 1024);
    gemm_lds<64, 64, 2, 2, 1, 1><<<dim3(8, 32, 1), 256, 0, stream>>>(
        tmp, W1T + w12Off, mid, b1 + l * 512, 1024, 1024, 1024, 512, 1, 0, 0, 0, 0, 0);
    gemm_lds<64, 64, 2, 2, 1, 0><<<dim3(16, 32, 1), 256, 0, stream>>>(
        mid, W2T + w12Off, h, b2 + l * 1024, 512, 512, 512, 1024, 1, 0, 0, 0, 0, 0);
    ln_kernel<<<2048, 256, 0, stream>>>(h, h, g2 + l * 1024, be2 + l * 1024);
  }
  gemm_lds<64, 64, 2, 2, 0, 0><<<dim3(4, 32, 1), 256, 0, stream>>>(
      h, WfT, (float*)d_out, bfv, 1024, 1024, 1024, 256, 1, 0, 0, 0, 0, 0);
}

// Round 4
// 1075.432 us; speedup vs baseline: 2.3472x; 1.1265x over previous
//
#include <hip/hip_runtime.h>
#include <hip/hip_bf16.h>

// ---------------------------------------------------------------------------
// ArrowTransformer forward: B=2, S=1024, D=1024, H=16, HD=64, L=6, V=256
// Round 3: attention KT=128 (<=2 serial iters/block), conflict-free V
// transpose staging, K staged via global_load_lds (chunked LDS layout),
// pre-skewed+prescaled Srel matrix (SM) written by the QE GEMM epilogue.
// ---------------------------------------------------------------------------

typedef __attribute__((ext_vector_type(8))) short  s8_t;
typedef __attribute__((ext_vector_type(4))) short  s4_t;
typedef __attribute__((ext_vector_type(8))) __bf16 bf8_t;
typedef __attribute__((ext_vector_type(4))) float  f4v;

static __device__ __forceinline__ short f2bf(float f) {
  union { float f; unsigned u; } a; a.f = f;
  unsigned u = a.u;
  u += 0x7fffu + ((u >> 16) & 1u);
  return (short)(u >> 16);
}
static __device__ __forceinline__ float bf2f(short s) {
  union { float f; unsigned u; } a;
  a.u = ((unsigned)(unsigned short)s) << 16;
  return a.f;
}
static __device__ __forceinline__ f4v mfma16(s8_t a, s8_t b, f4v c) {
  return __builtin_amdgcn_mfma_f32_16x16x32_bf16(
      __builtin_bit_cast(bf8_t, a), __builtin_bit_cast(bf8_t, b), c, 0, 0, 0);
}
static __device__ __forceinline__ void gld16(const short* g, short* l) {
  __builtin_amdgcn_global_load_lds(
      (const __attribute__((address_space(1))) void*)g,
      (__attribute__((address_space(3))) void*)l, 16, 0, 0);
}

// chunk table: heavy q-tiles first. nc(itile) = itile/4 + 1. chunk = 256 keys.
static __device__ const int IT_TAB[40] = {
  15,15,15,15, 14,14,14,14, 13,13,13,13, 12,12,12,12,
  11,11,11, 10,10,10, 9,9,9, 8,8,8,
  7,7, 6,6, 5,5, 4,4, 3, 2, 1, 0};
static __device__ const int CW_TAB[40] = {
  0,1,2,3, 0,1,2,3, 0,1,2,3, 0,1,2,3,
  0,1,2, 0,1,2, 0,1,2, 0,1,2,
  0,1, 0,1, 0,1, 0,1, 0, 0, 0, 0};

// ---------------------------------------------------------------------------
__global__ void transpose_bf16(const float* __restrict__ in, short* __restrict__ out,
                               int R, int C, long outBS, int outRowOff) {
  __shared__ float tile[32][33];
  const long zi = (long)blockIdx.z * R * C;
  out += (long)blockIdx.z * outBS + (long)outRowOff * R;
  const int c0 = blockIdx.x * 32, r0 = blockIdx.y * 32;
  const int tx = threadIdx.x, ty = threadIdx.y;
#pragma unroll
  for (int i = 0; i < 4; i++)
    tile[ty + i * 8][tx] = in[zi + (long)(r0 + ty + i * 8) * C + c0 + tx];
  __syncthreads();
#pragma unroll
  for (int i = 0; i < 4; i++)
    out[(long)(c0 + ty + i * 8) * R + r0 + tx] = f2bf(tile[tx][ty + i * 8]);
}

__global__ __launch_bounds__(256) void cvt_bf16(const float* __restrict__ in,
                                                short* __restrict__ out) {
  const long i = ((long)blockIdx.x * 256 + threadIdx.x) * 4;
  const float4 t = *(const float4*)(in + i);
  s4_t o = {f2bf(t.x), f2bf(t.y), f2bf(t.z), f2bf(t.w)};
  *(s4_t*)(out + i) = o;
}

__global__ void qkv_bias_kernel(const float* __restrict__ bq, const float* __restrict__ bk,
                                const float* __restrict__ bv, float* __restrict__ out) {
  const int idx = blockIdx.x * 256 + threadIdx.x;
  const int l = idx / 3072, n = idx % 3072;
  float v = (n < 1024) ? bq[l * 1024 + n]
          : (n < 2048) ? bk[l * 1024 + n - 1024]
                       : bv[l * 1024 + n - 2048];
  out[idx] = v;
}

__global__ void fnp_kernel(const int* __restrict__ x, int* __restrict__ fnp) {
  const int b = blockIdx.x, lane = threadIdx.x;
  int first = 1024;
  for (int j0 = 0; j0 < 1024; j0 += 64) {
    unsigned long long m = __ballot(x[b * 1024 + j0 + lane] != 0);
    if (m) { first = j0 + __ffsll(m) - 1; break; }
  }
  if (lane == 0) fnp[b] = first;
}

__global__ __launch_bounds__(256) void embed_kernel(const int* __restrict__ x,
                                                    const float* __restrict__ emb,
                                                    short* __restrict__ h) {
  const int row = blockIdx.x;
  const int s = row & 1023;
  const int xv = x[row];
  const int c = threadIdx.x << 2;
  const float4 e = *(const float4*)(emb + (long)xv * 1024 + c);
  const float ev[4] = {e.x, e.y, e.z, e.w};
  s4_t o;
#pragma unroll
  for (int i = 0; i < 4; i++) {
    const int d = c + i;
    const float par = (float)(d & 1);
    const float rate = expf(-9.210340371976184f * (float)d / 1024.0f) *
                       expf(9.210340371976184f * par / 1024.0f);
    const float pe = sinf((float)s * rate + 1.5707963267948966f * par);
    o[i] = f2bf(ev[i] * 32.0f + pe);
  }
  *(s4_t*)(h + (long)row * 1024 + c) = o;
}

__global__ __launch_bounds__(256) void ln_kernel(const short* __restrict__ in,
                                                 short* __restrict__ out,
                                                 const float* __restrict__ g,
                                                 const float* __restrict__ be) {
  __shared__ float red[4];
  __shared__ float red2[4];
  const int row = blockIdx.x;
  const int tid = threadIdx.x;
  const int c = tid << 2;
  const s4_t xv = *(const s4_t*)(in + (long)row * 1024 + c);
  const float x0 = bf2f(xv[0]), x1 = bf2f(xv[1]), x2 = bf2f(xv[2]), x3 = bf2f(xv[3]);
  float s = x0 + x1 + x2 + x3;
#pragma unroll
  for (int off = 1; off < 64; off <<= 1) s += __shfl_xor(s, off);
  const int wave = tid >> 6, lane = tid & 63;
  if (lane == 0) red[wave] = s;
  __syncthreads();
  const float mu = (red[0] + red[1] + red[2] + red[3]) * (1.0f / 1024.0f);
  const float d0 = x0 - mu, d1 = x1 - mu, d2 = x2 - mu, d3 = x3 - mu;
  float q = d0 * d0 + d1 * d1 + d2 * d2 + d3 * d3;
#pragma unroll
  for (int off = 1; off < 64; off <<= 1) q += __shfl_xor(q, off);
  if (lane == 0) red2[wave] = q;
  __syncthreads();
  const float var = (red2[0] + red2[1] + red2[2] + red2[3]) * (1.0f / 1024.0f);
  const float rs = rsqrtf(var + 1e-6f);
  const float4 gv = *(const float4*)(g + c);
  const float4 bv = *(const float4*)(be + c);
  s4_t o = {f2bf(d0 * rs * gv.x + bv.x), f2bf(d1 * rs * gv.y + bv.y),
            f2bf(d2 * rs * gv.z + bv.z), f2bf(d3 * rs * gv.w + bv.w)};
  *(s4_t*)(out + (long)row * 1024 + c) = o;
}

// ---------------------------------------------------------------------------
// Generic MFMA GEMM: C[m][n] = sum_k A[m][k]*BT[n][k] (+bias) (+relu)
// SKEW=1: Music-Transformer skew epilogue -> SM[i][j] = acc*0.125 at
// j = n-1023+i (write iff j>=0); used for the rel-pos matrix.
// ---------------------------------------------------------------------------
template <int BM, int BN, int WR, int WC, int OUT_BF16, int RELU, int SKEW = 0>
__global__ __launch_bounds__(256) void gemm_lds(
    const short* __restrict__ A, const short* __restrict__ BT,
    void* __restrict__ Cv, const float* __restrict__ biasp,
    int K, int lda, int ldb, int ldc,
    int batH, long sA1, long sA2, long sBT, long sC, int qeSkip) {
  constexpr int AR = BM / 64, BR = BN / 64;
  constexpr int FI = BM / WR / 16, FJ = BN / WC / 16;
  __shared__ short As[BM * 32];
  __shared__ short Bs[BN * 32];
  const int bm = blockIdx.y * BM, bn = blockIdx.x * BN;
  if (qeSkip && (bm + bn + BM + BN - 2 < 1023)) return;
  const int tid = threadIdx.x;
  const int z = blockIdx.z;
  const int wave = tid >> 6, lane = tid & 63;
  const int quad = lane >> 4, l16 = lane & 15;
  const int wr = wave / WC, wc = wave % WC;
  const int wm = wr * (BM / WR), wn = wc * (BN / WC);

  const short* Az = A + (long)(z / batH) * sA1 + (long)(z % batH) * sA2;
  const short* Bz = BT + (long)z * sBT;
  const short* Ag = Az + (long)(bm + wave * 16 + (lane >> 2)) * lda + ((lane & 3) << 3);
  const short* Bg = Bz + (long)(bn + wave * 16 + (lane >> 2)) * ldb + ((lane & 3) << 3);

  f4v acc[FI][FJ];
#pragma unroll
  for (int i = 0; i < FI; i++)
#pragma unroll
    for (int j = 0; j < FJ; j++) {
      f4v zz = {0.f, 0.f, 0.f, 0.f};
      acc[i][j] = zz;
    }

  for (int k0 = 0; k0 < K; k0 += 32) {
#pragma unroll
    for (int r = 0; r < AR; r++)
      gld16(Ag + (long)r * 64 * lda + k0, As + r * 2048 + wave * 512);
#pragma unroll
    for (int r = 0; r < BR; r++)
      gld16(Bg + (long)r * 64 * ldb + k0, Bs + r * 2048 + wave * 512);
    __syncthreads();
    s8_t af[FI], bfr[FJ];
#pragma unroll
    for (int t = 0; t < FI; t++)
      af[t] = *(const s8_t*)&As[(wm + t * 16 + l16) * 32 + quad * 8];
#pragma unroll
    for (int t = 0; t < FJ; t++)
      bfr[t] = *(const s8_t*)&Bs[(wn + t * 16 + l16) * 32 + quad * 8];
#pragma unroll
    for (int ti = 0; ti < FI; ti++)
#pragma unroll
      for (int tj = 0; tj < FJ; tj++)
        acc[ti][tj] = mfma16(af[ti], bfr[tj], acc[ti][tj]);
    __syncthreads();
  }

  char* Cb = (char*)Cv + (long)z * sC * (OUT_BF16 ? 2 : 4);
#pragma unroll
  for (int ti = 0; ti < FI; ti++) {
#pragma unroll
    for (int tj = 0; tj < FJ; tj++) {
      const int n = bn + wn + tj * 16 + l16;
      const float bval = (!SKEW && biasp) ? biasp[n] : 0.f;
#pragma unroll
      for (int r = 0; r < 4; r++) {
        const int m = bm + wm + ti * 16 + quad * 4 + r;
        if (SKEW) {
          const int j = n - 1023 + m;
          if (j >= 0)
            ((short*)Cb)[(long)m * ldc + j] = f2bf(acc[ti][tj][r] * 0.125f);
        } else {
          float vv = acc[ti][tj][r] + bval;
          if (RELU) vv = fmaxf(vv, 0.f);
          if (OUT_BF16) ((short*)Cb)[(long)m * ldc + n] = f2bf(vv);
          else          ((float*)Cb)[(long)m * ldc + n] = vv;
        }
      }
    }
  }
}

// ---------------------------------------------------------------------------
// Split-j attention main, KT=128: grid (B*H=32, 40 chunks). Block handles
// (bh, itile, cw) = 64 q-rows vs keys [cw*256, min(cw*256+256,(itile+1)*64)),
// <=2 iterations of 128 keys. Partials (m,l,O-f32) merged by attn_combine.
// ---------------------------------------------------------------------------
__global__ __launch_bounds__(256) void attn_main(
    const short* __restrict__ qkv, const short* __restrict__ SM,
    const int* __restrict__ xids,
    float* __restrict__ PO, float* __restrict__ PM, float* __restrict__ PL) {
  __shared__ short Ks2[8][128][8];   // [k-chunk][key][8 dims] (gld16 layout)
  __shared__ short Vt[64][136];      // [dim][key]
  __shared__ short Ps[4][16][136];   // per wave [row][key]
  __shared__ float kneg[128];

  const int bh = blockIdx.x, b = bh >> 4, hh = bh & 15;
  const int itile = IT_TAB[blockIdx.y], cw = CW_TAB[blockIdx.y];
  const int tid = threadIdx.x;
  const int wave = tid >> 6, lane = tid & 63, quad = lane >> 4, l16 = lane & 15;
  const int i0 = itile * 64 + wave * 16;

  s8_t aq[2];
  {
    const short* qp = qkv + ((long)(b * 1024 + i0 + l16)) * 3072 + hh * 64 + quad * 8;
    aq[0] = *(const s8_t*)qp;
    aq[1] = *(const s8_t*)(qp + 32);
  }

  f4v o[4];
#pragma unroll
  for (int nt = 0; nt < 4; nt++) { f4v zz = {0.f, 0.f, 0.f, 0.f}; o[nt] = zz; }
  float m_run[4] = {-INFINITY, -INFINITY, -INFINITY, -INFINITY};
  float l_run[4] = {0.f, 0.f, 0.f, 0.f};

  // staging assignments
  const int half = wave >> 1;                  // V: dims half
  const int krow = ((wave & 1) << 6) + lane;   // V: key row, spans 64/wave
  const short* kgl = qkv + ((long)b * 1024 + lane) * 3072 + 1024 + hh * 64 + wave * 8;
  const short* vgw = qkv + ((long)(b * 1024 + krow)) * 3072 + 2048 + hh * 64 + half * 32;

  const int irow = i0 + quad * 4;
  const short* smr[4];
#pragma unroll
  for (int r = 0; r < 4; r++)
    smr[r] = SM + ((long)bh * 1024 + irow + r) * 1024;

  const int jBeg = cw * 256;
  const int jEnd = min(cw * 256 + 256, itile * 64 + 64);

  for (int j0 = jBeg; j0 < jEnd; j0 += 128) {
    const long jrow = (long)j0 * 3072;
    // K -> LDS via async global_load_lds (4 calls/wave)
    gld16(kgl + jrow, &Ks2[wave][0][0]);
    gld16(kgl + jrow + (long)64 * 3072, &Ks2[wave][64][0]);
    gld16(kgl + jrow + 32, &Ks2[wave + 4][0][0]);
    gld16(kgl + jrow + (long)64 * 3072 + 32, &Ks2[wave + 4][64][0]);
    // V -> LDS transposed (krow spans 64 per wave -> conflict-free columns)
    {
      const short* vrow = vgw + jrow;
      const s8_t v0 = *(const s8_t*)(vrow);
      const s8_t v1 = *(const s8_t*)(vrow + 8);
      const s8_t v2 = *(const s8_t*)(vrow + 16);
      const s8_t v3 = *(const s8_t*)(vrow + 24);
#pragma unroll
      for (int t = 0; t < 8; t++) {
        Vt[half * 32 + t][krow] = v0[t];
        Vt[half * 32 + 8 + t][krow] = v1[t];
        Vt[half * 32 + 16 + t][krow] = v2[t];
        Vt[half * 32 + 24 + t][krow] = v3[t];
      }
    }
    if (tid < 128) kneg[tid] = (xids[b * 1024 + j0 + tid] == 0) ? -1e9f : 0.0f;
    __syncthreads();

    // ---- scores 16x128 + rel-pos + mask ----
    float p[8][4];
#pragma unroll
    for (int jt = 0; jt < 8; jt++) {
      const s8_t k0f = *(const s8_t*)&Ks2[quad][jt * 16 + l16][0];
      const s8_t k1f = *(const s8_t*)&Ks2[4 + quad][jt * 16 + l16][0];
      f4v zz = {0.f, 0.f, 0.f, 0.f};
      zz = mfma16(aq[0], k0f, zz);
      zz = mfma16(aq[1], k1f, zz);
      const int j = j0 + jt * 16 + l16;
      const float kn = kneg[jt * 16 + l16];
#pragma unroll
      for (int r = 0; r < 4; r++) {
        const float add = bf2f(smr[r][j]) + kn;
        p[jt][r] = zz[r] * 0.125f + ((j <= irow + r) ? add : -1e9f);
      }
    }

    // ---- online softmax (one round per 128 keys) ----
    float alpha[4];
#pragma unroll
    for (int r = 0; r < 4; r++) {
      float mx = p[0][r];
#pragma unroll
      for (int jt = 1; jt < 8; jt++) mx = fmaxf(mx, p[jt][r]);
      mx = fmaxf(mx, __shfl_xor(mx, 1));
      mx = fmaxf(mx, __shfl_xor(mx, 2));
      mx = fmaxf(mx, __shfl_xor(mx, 4));
      mx = fmaxf(mx, __shfl_xor(mx, 8));
      const float mnew = fmaxf(m_run[r], mx);
      alpha[r] = expf(m_run[r] - mnew);
      float ps = 0.f;
#pragma unroll
      for (int jt = 0; jt < 8; jt++) {
        p[jt][r] = expf(p[jt][r] - mnew);
        ps += p[jt][r];
      }
      ps += __shfl_xor(ps, 1);
      ps += __shfl_xor(ps, 2);
      ps += __shfl_xor(ps, 4);
      ps += __shfl_xor(ps, 8);
      l_run[r] = l_run[r] * alpha[r] + ps;
      m_run[r] = mnew;
    }

    // ---- P -> LDS (A-layout), rescale O ----
#pragma unroll
    for (int jt = 0; jt < 8; jt++)
#pragma unroll
      for (int r = 0; r < 4; r++)
        Ps[wave][quad * 4 + r][jt * 16 + l16] = f2bf(p[jt][r]);
#pragma unroll
    for (int nt = 0; nt < 4; nt++)
#pragma unroll
      for (int r = 0; r < 4; r++)
        o[nt][r] *= alpha[r];

    // ---- O += P @ V (K=128) ----
#pragma unroll
    for (int ks4 = 0; ks4 < 4; ks4++) {
      const s8_t ap = *(const s8_t*)&Ps[wave][l16][ks4 * 32 + quad * 8];
#pragma unroll
      for (int nt = 0; nt < 4; nt++) {
        const s8_t vf = *(const s8_t*)&Vt[nt * 16 + l16][ks4 * 32 + quad * 8];
        o[nt] = mfma16(ap, vf, o[nt]);
      }
    }
    __syncthreads();
  }

  const long part = (long)(bh * 16 + itile) * 4 + cw;
  float* po = PO + part * 4096;
#pragma unroll
  for (int nt = 0; nt < 4; nt++) {
#pragma unroll
    for (int r = 0; r < 4; r++) {
      const int row = wave * 16 + quad * 4 + r;
      po[row * 64 + nt * 16 + l16] = o[nt][r];
    }
  }
  if (l16 == 0) {
#pragma unroll
    for (int r = 0; r < 4; r++) {
      const int row = wave * 16 + quad * 4 + r;
      PM[part * 64 + row] = m_run[r];
      PL[part * 64 + row] = l_run[r];
    }
  }
}

// combine partial chunks -> output. grid 512 blocks (bh*16+itile), 256 thr.
__global__ __launch_bounds__(256) void attn_combine(
    const float* __restrict__ PO, const float* __restrict__ PM,
    const float* __restrict__ PL, short* __restrict__ outb) {
  const int id = blockIdx.x;
  const int bh = id >> 4, itile = id & 15;
  const int b = bh >> 4, hh = bh & 15;
  const int nc = (itile >> 2) + 1;
  const int row = threadIdx.x >> 2, seg = (threadIdx.x & 3) << 4;
  const long base = (long)id * 4;

  float mv[4];
  float M = -INFINITY;
  for (int c = 0; c < nc; c++) {
    mv[c] = PM[(base + c) * 64 + row];
    M = fmaxf(M, mv[c]);
  }
  f4v acc[4];
#pragma unroll
  for (int t = 0; t < 4; t++) { f4v zz = {0.f, 0.f, 0.f, 0.f}; acc[t] = zz; }
  float l = 0.f;
  for (int c = 0; c < nc; c++) {
    const float w = expf(mv[c] - M);
    l += w * PL[(base + c) * 64 + row];
    const float* po = PO + (base + c) * 4096 + row * 64 + seg;
#pragma unroll
    for (int t = 0; t < 4; t++) {
      const f4v v = *(const f4v*)(po + t * 4);
      acc[t] += w * v;
    }
  }
  const float inv = 1.0f / l;
  const int i = itile * 64 + row;
  short* op = outb + ((long)(b * 1024 + i)) * 1024 + hh * 64 + seg;
#pragma unroll
  for (int t = 0; t < 4; t++) {
    s4_t o = {f2bf(acc[t][0] * inv), f2bf(acc[t][1] * inv),
              f2bf(acc[t][2] * inv), f2bf(acc[t][3] * inv)};
    *(s4_t*)(op + t * 4) = o;
  }
}

// ---------------------------------------------------------------------------
// Pad fallback (rare): rows i < fnp[b] are fully masked -> reference softmax
// equals UNMASKED attention over all keys. Early-exits when fnp[b]==0.
// ---------------------------------------------------------------------------
__global__ __launch_bounds__(256) void attn_fallback(
    const short* __restrict__ qkv, const short* __restrict__ SM,
    const int* __restrict__ fnp, short* __restrict__ outb) {
  const int bh = blockIdx.x, b = bh >> 4, hh = bh & 15;
  const int itile = blockIdx.y;
  const int fb = fnp[b];
  if (fb <= itile * 64) return;

  __shared__ short Ks[64][72];
  __shared__ short Vt[64][72];
  __shared__ short Ps[4][16][72];

  const int tid = threadIdx.x;
  const int wave = tid >> 6, lane = tid & 63, quad = lane >> 4, l16 = lane & 15;
  const int i0 = itile * 64 + wave * 16;

  s8_t aq[2];
  {
    const short* qp = qkv + ((long)(b * 1024 + i0 + l16)) * 3072 + hh * 64 + quad * 8;
    aq[0] = *(const s8_t*)qp;
    aq[1] = *(const s8_t*)(qp + 32);
  }
  f4v o[4];
#pragma unroll
  for (int nt = 0; nt < 4; nt++) { f4v zz = {0.f, 0.f, 0.f, 0.f}; o[nt] = zz; }
  float m_run[4] = {-INFINITY, -INFINITY, -INFINITY, -INFINITY};
  float l_run[4] = {0.f, 0.f, 0.f, 0.f};

  const int jr = tid >> 2, c0 = (tid & 3) << 4;
  const short* kp0 = qkv + ((long)(b * 1024 + jr)) * 3072 + 1024 + hh * 64 + c0;
  const short* vp0 = kp0 + 1024;

  for (int j0 = 0; j0 < 1024; j0 += 64) {
    const long joff = (long)j0 * 3072;
    *(s8_t*)&Ks[jr][c0] = *(const s8_t*)(kp0 + joff);
    *(s8_t*)&Ks[jr][c0 + 8] = *(const s8_t*)(kp0 + joff + 8);
    const s8_t v0 = *(const s8_t*)(vp0 + joff);
    const s8_t v1 = *(const s8_t*)(vp0 + joff + 8);
#pragma unroll
    for (int t = 0; t < 8; t++) {
      Vt[c0 + t][jr] = v0[t];
      Vt[c0 + 8 + t][jr] = v1[t];
    }
    __syncthreads();

    f4v sc[4];
#pragma unroll
    for (int nt = 0; nt < 4; nt++) {
      const s8_t k0f = *(const s8_t*)&Ks[nt * 16 + l16][quad * 8];
      const s8_t k1f = *(const s8_t*)&Ks[nt * 16 + l16][32 + quad * 8];
      f4v zz = {0.f, 0.f, 0.f, 0.f};
      zz = mfma16(aq[0], k0f, zz);
      zz = mfma16(aq[1], k1f, zz);
      sc[nt] = zz;
    }
    float p[4][4];
    const int irow = i0 + quad * 4;
#pragma unroll
    for (int nt = 0; nt < 4; nt++) {
      const int j = j0 + nt * 16 + l16;
#pragma unroll
      for (int r = 0; r < 4; r++) {
        const int i = irow + r;
        const float smv = bf2f(SM[((long)bh * 1024 + i) * 1024 + j]);
        p[nt][r] = sc[nt][r] * 0.125f + ((j <= i) ? smv : 0.f);
      }
    }
    float alpha[4];
#pragma unroll
    for (int r = 0; r < 4; r++) {
      float mx = fmaxf(fmaxf(p[0][r], p[1][r]), fmaxf(p[2][r], p[3][r]));
      mx = fmaxf(mx, __shfl_xor(mx, 1));
      mx = fmaxf(mx, __shfl_xor(mx, 2));
      mx = fmaxf(mx, __shfl_xor(mx, 4));
      mx = fmaxf(mx, __shfl_xor(mx, 8));
      const float mnew = fmaxf(m_run[r], mx);
      alpha[r] = expf(m_run[r] - mnew);
      float ps = 0.f;
#pragma unroll
      for (int nt = 0; nt < 4; nt++) {
        p[nt][r] = expf(p[nt][r] - mnew);
        ps += p[nt][r];
      }
      ps += __shfl_xor(ps, 1);
      ps += __shfl_xor(ps, 2);
      ps += __shfl_xor(ps, 4);
      ps += __shfl_xor(ps, 8);
      l_run[r] = l_run[r] * alpha[r] + ps;
      m_run[r] = mnew;
    }
#pragma unroll
    for (int nt = 0; nt < 4; nt++) {
#pragma unroll
      for (int r = 0; r < 4; r++) {
        Ps[wave][quad * 4 + r][nt * 16 + l16] = f2bf(p[nt][r]);
        o[nt][r] *= alpha[r];
      }
    }
#pragma unroll
    for (int ks = 0; ks < 2; ks++) {
      const s8_t ap = *(const s8_t*)&Ps[wave][l16][ks * 32 + quad * 8];
#pragma unroll
      for (int nt = 0; nt < 4; nt++) {
        const s8_t vf = *(const s8_t*)&Vt[nt * 16 + l16][ks * 32 + quad * 8];
        o[nt] = mfma16(ap, vf, o[nt]);
      }
    }
    __syncthreads();
  }

#pragma unroll
  for (int nt = 0; nt < 4; nt++) {
#pragma unroll
    for (int r = 0; r < 4; r++) {
      const int i = i0 + quad * 4 + r;
      if (i < fb)
        outb[((long)(b * 1024 + i)) * 1024 + hh * 64 + nt * 16 + l16] =
            f2bf(o[nt][r] / l_run[r]);
    }
  }
}

// ---------------------------------------------------------------------------
extern "C" void kernel_launch(void* const* d_in, const int* in_sizes, int n_in,
                              void* d_out, int out_size, void* d_ws, size_t ws_size,
                              hipStream_t stream) {
  const int*   x   = (const int*)d_in[0];
  const float* emb = (const float*)d_in[1];
  const float* Wq  = (const float*)d_in[2];
  const float* bq  = (const float*)d_in[3];
  const float* Wk  = (const float*)d_in[4];
  const float* bk  = (const float*)d_in[5];
  const float* Wv  = (const float*)d_in[6];
  const float* bv  = (const float*)d_in[7];
  const float* Wo  = (const float*)d_in[8];
  const float* bo  = (const float*)d_in[9];
  const float* W1  = (const float*)d_in[10];
  const float* b1  = (const float*)d_in[11];
  const float* W2  = (const float*)d_in[12];
  const float* b2  = (const float*)d_in[13];
  const float* g1  = (const float*)d_in[14];
  const float* be1 = (const float*)d_in[15];
  const float* g2  = (const float*)d_in[16];
  const float* be2 = (const float*)d_in[17];
  const float* E   = (const float*)d_in[18];
  const float* Wf  = (const float*)d_in[19];
  const float* bfv = (const float*)d_in[20];

  char* p = (char*)d_ws;
  auto alloc = [&](size_t bytes) {
    char* r = p;
    p += (bytes + 255) & ~(size_t)255;
    return r;
  };
  short* h    = (short*)alloc(2048ull * 1024 * 2);
  short* qkv  = (short*)alloc(2048ull * 3072 * 2);
  short* attn = (short*)alloc(2048ull * 1024 * 2);
  short* tmp  = (short*)alloc(2048ull * 1024 * 2);
  short* mid  = (short*)alloc(2048ull * 512 * 2);
  short* SMb  = (short*)alloc(32ull * 1024 * 1024 * 2);
  short* qkvT = (short*)alloc(6ull * 3072 * 1024 * 2);
  short* WoT  = (short*)alloc(6ull * 1024 * 1024 * 2);
  short* W1T  = (short*)alloc(6ull * 512 * 1024 * 2);
  short* W2T  = (short*)alloc(6ull * 1024 * 512 * 2);
  short* WfT  = (short*)alloc(256ull * 1024 * 2);
  short* Ebf  = (short*)alloc(6ull * 1024 * 64 * 2);
  float* qkvB = (float*)alloc(6ull * 3072 * 4);
  int*   fnp  = (int*)alloc(256);
  float* PO   = (float*)alloc(2048ull * 4096 * 4);
  float* PM   = (float*)alloc(2048ull * 64 * 4);
  float* PL   = (float*)alloc(2048ull * 64 * 4);

  const dim3 tb(32, 8);
  transpose_bf16<<<dim3(32, 32, 6), tb, 0, stream>>>(Wq, qkvT, 1024, 1024, 3072 * 1024, 0);
  transpose_bf16<<<dim3(32, 32, 6), tb, 0, stream>>>(Wk, qkvT, 1024, 1024, 3072 * 1024, 1024);
  transpose_bf16<<<dim3(32, 32, 6), tb, 0, stream>>>(Wv, qkvT, 1024, 1024, 3072 * 1024, 2048);
  transpose_bf16<<<dim3(32, 32, 6), tb, 0, stream>>>(Wo, WoT, 1024, 1024, 1024 * 1024, 0);
  transpose_bf16<<<dim3(16, 32, 6), tb, 0, stream>>>(W1, W1T, 1024, 512, 512 * 1024, 0);
  transpose_bf16<<<dim3(32, 16, 6), tb, 0, stream>>>(W2, W2T, 512, 1024, 1024 * 512, 0);
  transpose_bf16<<<dim3(8, 32, 1), tb, 0, stream>>>(Wf, WfT, 1024, 256, 256 * 1024, 0);
  cvt_bf16<<<384, 256, 0, stream>>>(E, Ebf);
  qkv_bias_kernel<<<72, 256, 0, stream>>>(bq, bk, bv, qkvB);
  fnp_kernel<<<2, 64, 0, stream>>>(x, fnp);
  embed_kernel<<<2048, 256, 0, stream>>>(x, emb, h);

  for (int l = 0; l < 6; l++) {
    const long wOff = (long)l * 1024 * 1024;
    const long w12Off = (long)l * 512 * 1024;
    gemm_lds<128, 128, 2, 2, 1, 0><<<dim3(24, 16, 1), 256, 0, stream>>>(
        h, qkvT + (long)l * 3072 * 1024, qkv, qkvB + l * 3072,
        1024, 1024, 1024, 3072, 1, 0, 0, 0, 0, 0);
    // rel-pos: SM[bh][i][j] = (q_i . E[1023-i+j]) * 0.125, causal half only
    gemm_lds<128, 128, 2, 2, 1, 0, 1><<<dim3(8, 8, 32), 256, 0, stream>>>(
        qkv, Ebf + (long)l * 1024 * 64, SMb, nullptr,
        64, 3072, 64, 1024, 16, (long)1024 * 3072, 64, 0, (long)1024 * 1024, 1);
    attn_main<<<dim3(32, 40), 256, 0, stream>>>(qkv, SMb, x, PO, PM, PL);
    attn_combine<<<512, 256, 0, stream>>>(PO, PM, PL, attn);
    attn_fallback<<<dim3(32, 16), 256, 0, stream>>>(qkv, SMb, fnp, attn);
    gemm_lds<64, 64, 2, 2, 1, 0><<<dim3(16, 32, 1), 256, 0, stream>>>(
        attn, WoT + wOff, tmp, bo + l * 1024, 1024, 1024, 1024, 1024, 1, 0, 0, 0, 0, 0);
    ln_kernel<<<2048, 256, 0, stream>>>(tmp, tmp, g1 + l * 1024, be1 + l * 1024);
    gemm_lds<64, 64, 2, 2, 1, 1><<<dim3(8, 32, 1), 256, 0, stream>>>(
        tmp, W1T + w12Off, mid, b1 + l * 512, 1024, 1024, 1024, 512, 1, 0, 0, 0, 0, 0);
    gemm_lds<64, 64, 2, 2, 1, 0><<<dim3(16, 32, 1), 256, 0, stream>>>(
        mid, W2T + w12Off, h, b2 + l * 1024, 512, 512, 512, 1024, 1, 0, 0, 0, 0, 0);
    ln_kernel<<<2048, 256, 0, stream>>>(h, h, g2 + l * 1024, be2 + l * 1024);
  }
  gemm_lds<64, 64, 2, 2, 0, 0><<<dim3(4, 32, 1), 256, 0, stream>>>(
      h, WfT, (float*)d_out, bfv, 1024, 1024, 1024, 256, 1, 0, 0, 0, 0, 0);
}

// Round 5
// 978.783 us; speedup vs baseline: 2.5790x; 1.0987x over previous
//
#include <hip/hip_runtime.h>
#include <hip/hip_bf16.h>

// ---------------------------------------------------------------------------
// ArrowTransformer forward: B=2, S=1024, D=1024, H=16, HD=64, L=6, V=256
// Round 4: QE/Srel fused into attn_main (MFMA G-band per wave, no SM buffer),
// fallback merged into attn_main grid, prep kernels merged (51 dispatches),
// OOB clamps on key staging.
// ---------------------------------------------------------------------------

typedef __attribute__((ext_vector_type(8))) short  s8_t;
typedef __attribute__((ext_vector_type(4))) short  s4_t;
typedef __attribute__((ext_vector_type(8))) __bf16 bf8_t;
typedef __attribute__((ext_vector_type(4))) float  f4v;

static __device__ __forceinline__ short f2bf(float f) {
  union { float f; unsigned u; } a; a.f = f;
  unsigned u = a.u;
  u += 0x7fffu + ((u >> 16) & 1u);
  return (short)(u >> 16);
}
static __device__ __forceinline__ float bf2f(short s) {
  union { float f; unsigned u; } a;
  a.u = ((unsigned)(unsigned short)s) << 16;
  return a.f;
}
static __device__ __forceinline__ f4v mfma16(s8_t a, s8_t b, f4v c) {
  return __builtin_amdgcn_mfma_f32_16x16x32_bf16(
      __builtin_bit_cast(bf8_t, a), __builtin_bit_cast(bf8_t, b), c, 0, 0, 0);
}
static __device__ __forceinline__ void gld16(const short* g, short* l) {
  __builtin_amdgcn_global_load_lds(
      (const __attribute__((address_space(1))) void*)g,
      (__attribute__((address_space(3))) void*)l, 16, 0, 0);
}

// chunk table: heavy q-tiles first. nc(itile) = itile/4 + 1. chunk = 256 keys.
static __device__ const int IT_TAB[40] = {
  15,15,15,15, 14,14,14,14, 13,13,13,13, 12,12,12,12,
  11,11,11, 10,10,10, 9,9,9, 8,8,8,
  7,7, 6,6, 5,5, 4,4, 3, 2, 1, 0};
static __device__ const int CW_TAB[40] = {
  0,1,2,3, 0,1,2,3, 0,1,2,3, 0,1,2,3,
  0,1,2, 0,1,2, 0,1,2, 0,1,2,
  0,1, 0,1, 0,1, 0,1, 0, 0, 0, 0};

// ---------------------------------------------------------------------------
// Unified weight prep: all transposes (f32 -> bf16, [N][K] layout).
// grid 30976 x (32,8).
// ---------------------------------------------------------------------------
__global__ void prep_weights(
    const float* __restrict__ Wq, const float* __restrict__ Wk,
    const float* __restrict__ Wv, const float* __restrict__ Wo,
    const float* __restrict__ W1, const float* __restrict__ W2,
    const float* __restrict__ Wf,
    short* __restrict__ qkvT, short* __restrict__ WoT, short* __restrict__ W1T,
    short* __restrict__ W2T, short* __restrict__ WfT) {
  __shared__ float tile[32][33];
  int z = blockIdx.x;
  const float* in; short* out; int R, C; long outBS; int rowOff = 0;
  if (z < 18432) {
    R = 1024; C = 1024; outBS = (long)3072 * 1024; out = qkvT;
    if (z < 6144)       { in = Wq; }
    else if (z < 12288) { in = Wk; rowOff = 1024; z -= 6144; }
    else                { in = Wv; rowOff = 2048; z -= 12288; }
  } else if (z < 24576) { in = Wo; out = WoT; R = 1024; C = 1024; outBS = (long)1024 * 1024; z -= 18432; }
  else if (z < 27648)   { in = W1; out = W1T; R = 1024; C = 512;  outBS = (long)512 * 1024;  z -= 24576; }
  else if (z < 30720)   { in = W2; out = W2T; R = 512;  C = 1024; outBS = (long)1024 * 512;  z -= 27648; }
  else                  { in = Wf; out = WfT; R = 1024; C = 256;  outBS = 0;                 z -= 30720; }
  const int nx = C >> 5, ny = R >> 5;
  const int per = nx * ny;
  const int l = z / per, rem = z % per;
  const int cx = rem % nx, cy = rem / nx;
  in += (long)l * R * C;
  out += (long)l * outBS + (long)rowOff * R;
  const int c0 = cx * 32, r0 = cy * 32;
  const int tx = threadIdx.x, ty = threadIdx.y;
#pragma unroll
  for (int i = 0; i < 4; i++)
    tile[ty + i * 8][tx] = in[(long)(r0 + ty + i * 8) * C + c0 + tx];
  __syncthreads();
#pragma unroll
  for (int i = 0; i < 4; i++)
    out[(long)(c0 + ty + i * 8) * R + r0 + tx] = f2bf(tile[tx][ty + i * 8]);
}

// ---------------------------------------------------------------------------
// Misc prep: embed+PE (blocks 0..2047), E->bf16 (2048..2431),
// qkv bias concat (2432..2503), fnp (2504..2505). 256 threads.
// ---------------------------------------------------------------------------
__global__ __launch_bounds__(256) void prep_misc(
    const int* __restrict__ x, const float* __restrict__ emb,
    const float* __restrict__ E,
    const float* __restrict__ bq, const float* __restrict__ bk,
    const float* __restrict__ bv,
    short* __restrict__ h, short* __restrict__ Ebf,
    float* __restrict__ qkvB, int* __restrict__ fnp) {
  const int z = blockIdx.x;
  const int tid = threadIdx.x;
  if (z < 2048) {
    const int s = z & 1023;
    const int xv = x[z];
    const int c = tid << 2;
    const float4 e = *(const float4*)(emb + (long)xv * 1024 + c);
    const float ev[4] = {e.x, e.y, e.z, e.w};
    s4_t o;
#pragma unroll
    for (int i = 0; i < 4; i++) {
      const int d = c + i;
      const float par = (float)(d & 1);
      const float rate = expf(-9.210340371976184f * (float)d / 1024.0f) *
                         expf(9.210340371976184f * par / 1024.0f);
      const float pe = sinf((float)s * rate + 1.5707963267948966f * par);
      o[i] = f2bf(ev[i] * 32.0f + pe);
    }
    *(s4_t*)(h + (long)z * 1024 + c) = o;
  } else if (z < 2432) {
    const long i = ((long)(z - 2048) * 256 + tid) * 4;
    const float4 t = *(const float4*)(E + i);
    s4_t o = {f2bf(t.x), f2bf(t.y), f2bf(t.z), f2bf(t.w)};
    *(s4_t*)(Ebf + i) = o;
  } else if (z < 2504) {
    const int idx = (z - 2432) * 256 + tid;
    const int l = idx / 3072, n = idx % 3072;
    float v = (n < 1024) ? bq[l * 1024 + n]
            : (n < 2048) ? bk[l * 1024 + n - 1024]
                         : bv[l * 1024 + n - 2048];
    qkvB[idx] = v;
  } else {
    if (tid < 64) {
      const int b = z - 2504;
      int first = 1024;
      for (int j0 = 0; j0 < 1024; j0 += 64) {
        unsigned long long m = __ballot(x[b * 1024 + j0 + tid] != 0);
        if (m) { first = j0 + __ffsll(m) - 1; break; }
      }
      if (tid == 0) fnp[b] = first;
    }
  }
}

// ---------------------------------------------------------------------------
// LayerNorm over D=1024, bf16 in/out. One block per row. In-place safe.
// ---------------------------------------------------------------------------
__global__ __launch_bounds__(256) void ln_kernel(const short* __restrict__ in,
                                                 short* __restrict__ out,
                                                 const float* __restrict__ g,
                                                 const float* __restrict__ be) {
  __shared__ float red[4];
  __shared__ float red2[4];
  const int row = blockIdx.x;
  const int tid = threadIdx.x;
  const int c = tid << 2;
  const s4_t xv = *(const s4_t*)(in + (long)row * 1024 + c);
  const float x0 = bf2f(xv[0]), x1 = bf2f(xv[1]), x2 = bf2f(xv[2]), x3 = bf2f(xv[3]);
  float s = x0 + x1 + x2 + x3;
#pragma unroll
  for (int off = 1; off < 64; off <<= 1) s += __shfl_xor(s, off);
  const int wave = tid >> 6, lane = tid & 63;
  if (lane == 0) red[wave] = s;
  __syncthreads();
  const float mu = (red[0] + red[1] + red[2] + red[3]) * (1.0f / 1024.0f);
  const float d0 = x0 - mu, d1 = x1 - mu, d2 = x2 - mu, d3 = x3 - mu;
  float q = d0 * d0 + d1 * d1 + d2 * d2 + d3 * d3;
#pragma unroll
  for (int off = 1; off < 64; off <<= 1) q += __shfl_xor(q, off);
  if (lane == 0) red2[wave] = q;
  __syncthreads();
  const float var = (red2[0] + red2[1] + red2[2] + red2[3]) * (1.0f / 1024.0f);
  const float rs = rsqrtf(var + 1e-6f);
  const float4 gv = *(const float4*)(g + c);
  const float4 bv = *(const float4*)(be + c);
  s4_t o = {f2bf(d0 * rs * gv.x + bv.x), f2bf(d1 * rs * gv.y + bv.y),
            f2bf(d2 * rs * gv.z + bv.z), f2bf(d3 * rs * gv.w + bv.w)};
  *(s4_t*)(out + (long)row * 1024 + c) = o;
}

// ---------------------------------------------------------------------------
// Generic MFMA GEMM: C[m][n] = sum_k A[m][k]*BT[n][k] (+bias) (+relu)
// ---------------------------------------------------------------------------
template <int BM, int BN, int WR, int WC, int OUT_BF16, int RELU>
__global__ __launch_bounds__(256) void gemm_lds(
    const short* __restrict__ A, const short* __restrict__ BT,
    void* __restrict__ Cv, const float* __restrict__ biasp,
    int K, int lda, int ldb, int ldc) {
  constexpr int AR = BM / 64, BR = BN / 64;
  constexpr int FI = BM / WR / 16, FJ = BN / WC / 16;
  __shared__ short As[BM * 32];
  __shared__ short Bs[BN * 32];
  const int bm = blockIdx.y * BM, bn = blockIdx.x * BN;
  const int tid = threadIdx.x;
  const int wave = tid >> 6, lane = tid & 63;
  const int quad = lane >> 4, l16 = lane & 15;
  const int wr = wave / WC, wc = wave % WC;
  const int wm = wr * (BM / WR), wn = wc * (BN / WC);

  const short* Ag = A + (long)(bm + wave * 16 + (lane >> 2)) * lda + ((lane & 3) << 3);
  const short* Bg = BT + (long)(bn + wave * 16 + (lane >> 2)) * ldb + ((lane & 3) << 3);

  f4v acc[FI][FJ];
#pragma unroll
  for (int i = 0; i < FI; i++)
#pragma unroll
    for (int j = 0; j < FJ; j++) {
      f4v zz = {0.f, 0.f, 0.f, 0.f};
      acc[i][j] = zz;
    }

  for (int k0 = 0; k0 < K; k0 += 32) {
#pragma unroll
    for (int r = 0; r < AR; r++)
      gld16(Ag + (long)r * 64 * lda + k0, As + r * 2048 + wave * 512);
#pragma unroll
    for (int r = 0; r < BR; r++)
      gld16(Bg + (long)r * 64 * ldb + k0, Bs + r * 2048 + wave * 512);
    __syncthreads();
    s8_t af[FI], bfr[FJ];
#pragma unroll
    for (int t = 0; t < FI; t++)
      af[t] = *(const s8_t*)&As[(wm + t * 16 + l16) * 32 + quad * 8];
#pragma unroll
    for (int t = 0; t < FJ; t++)
      bfr[t] = *(const s8_t*)&Bs[(wn + t * 16 + l16) * 32 + quad * 8];
#pragma unroll
    for (int ti = 0; ti < FI; ti++)
#pragma unroll
      for (int tj = 0; tj < FJ; tj++)
        acc[ti][tj] = mfma16(af[ti], bfr[tj], acc[ti][tj]);
    __syncthreads();
  }

#pragma unroll
  for (int ti = 0; ti < FI; ti++) {
#pragma unroll
    for (int tj = 0; tj < FJ; tj++) {
      const int n = bn + wn + tj * 16 + l16;
      const float bval = biasp ? biasp[n] : 0.f;
#pragma unroll
      for (int r = 0; r < 4; r++) {
        const int m = bm + wm + ti * 16 + quad * 4 + r;
        float vv = acc[ti][tj][r] + bval;
        if (RELU) vv = fmaxf(vv, 0.f);
        if (OUT_BF16) ((short*)Cv)[(long)m * ldc + n] = f2bf(vv);
        else          ((float*)Cv)[(long)m * ldc + n] = vv;
      }
    }
  }
}

// ---------------------------------------------------------------------------
// Attention with fused rel-pos. grid (B*H=32, 56):
//  y in [0,40): split-j chunk path (itile, cw from tables); KT=128;
//     per wave, the needed Srel band G[i][m]=q_i.E_m is computed via MFMA
//     (9 16x16 tiles, E read as B-fragments from global) into the reused
//     P-buffer with per-wave col offset col' = 15 - row + (j - j0).
//     itile<4 (nc==1) writes output directly (rows i>=fnp only);
//     else writes partials PO/PM/PL.
//  y in [40,56): pad-fallback q-tile (itile = y-40): rows i<fnp[b] are fully
//     masked -> reference softmax = UNMASKED attention over all 1024 keys.
//     Early-exits when fnp[b] <= itile*64.
// ---------------------------------------------------------------------------
__global__ __launch_bounds__(256) void attn_main(
    const short* __restrict__ qkv, const short* __restrict__ Eb,
    const int* __restrict__ xids, const int* __restrict__ fnp,
    float* __restrict__ PO, float* __restrict__ PM, float* __restrict__ PL,
    short* __restrict__ outb) {
  __shared__ short Ks2[8][128][8];   // [k-chunk][key][8 dims] (gld16 layout)
  __shared__ short Vt[64][136];      // [dim][key]
  __shared__ short Gs[4][16][152];   // per wave: G band (cols 0..143), then P (cols 0..127)
  __shared__ float kneg[128];

  const int bh = blockIdx.x, b = bh >> 4, hh = bh & 15;
  const int yy = blockIdx.y;
  const bool fbp = (yy >= 40);
  const int itile = fbp ? (yy - 40) : IT_TAB[yy];
  const int cw = fbp ? 0 : CW_TAB[yy];
  const int fb = fnp[b];
  const int i0g = itile * 64;
  if (fbp && fb <= i0g) return;

  const int tid = threadIdx.x;
  const int wave = tid >> 6, lane = tid & 63, quad = lane >> 4, l16 = lane & 15;
  const int i0 = i0g + wave * 16;

  s8_t aq[2];
  {
    const short* qp = qkv + ((long)(b * 1024 + i0 + l16)) * 3072 + hh * 64 + quad * 8;
    aq[0] = *(const s8_t*)qp;
    aq[1] = *(const s8_t*)(qp + 32);
  }

  f4v o[4];
#pragma unroll
  for (int nt = 0; nt < 4; nt++) { f4v zz = {0.f, 0.f, 0.f, 0.f}; o[nt] = zz; }
  float m_run[4] = {-INFINITY, -INFINITY, -INFINITY, -INFINITY};
  float l_run[4] = {0.f, 0.f, 0.f, 0.f};

  const int half = wave >> 1;                  // V: dims half
  const int krow = ((wave & 1) << 6) + lane;   // V: key row within tile
  const short* kbase = qkv + (long)b * 1024 * 3072 + 1024 + hh * 64 + wave * 8;
  const short* vbase = qkv + (long)b * 1024 * 3072 + 2048 + hh * 64 + half * 32;
  short* gs = &Gs[wave][0][0];

  const int jBeg = fbp ? 0 : cw * 256;
  const int jEnd = fbp ? 1024 : min(cw * 256 + 256, i0g + 64);

  for (int j0 = jBeg; j0 < jEnd; j0 += 128) {
    // ---- K/V staging (clamped key indices; overshoot keys are masked) ----
    {
      const long k1 = min(j0 + lane, 1023);
      const long k2 = min(j0 + 64 + lane, 1023);
      gld16(kbase + k1 * 3072, &Ks2[wave][0][0]);
      gld16(kbase + k2 * 3072, &Ks2[wave][64][0]);
      gld16(kbase + k1 * 3072 + 32, &Ks2[wave + 4][0][0]);
      gld16(kbase + k2 * 3072 + 32, &Ks2[wave + 4][64][0]);
      const long kv = min(j0 + krow, 1023);
      const short* vrow = vbase + kv * 3072;
      const s8_t v0 = *(const s8_t*)(vrow);
      const s8_t v1 = *(const s8_t*)(vrow + 8);
      const s8_t v2 = *(const s8_t*)(vrow + 16);
      const s8_t v3 = *(const s8_t*)(vrow + 24);
#pragma unroll
      for (int t = 0; t < 8; t++) {
        Vt[half * 32 + t][krow] = v0[t];
        Vt[half * 32 + 8 + t][krow] = v1[t];
        Vt[half * 32 + 16 + t][krow] = v2[t];
        Vt[half * 32 + 24 + t][krow] = v3[t];
      }
    }
    if (tid < 128) kneg[tid] = (xids[b * 1024 + min(j0 + tid, 1023)] == 0) ? -1e9f : 0.0f;

    // ---- fused rel-pos band: G[row][col'] = q_(i0+row) . E_(mW+col') ----
    {
      const int mW = 1008 - i0g - wave * 16 + j0;
#pragma unroll
      for (int t = 0; t < 9; t++) {
        const int m = min(mW + t * 16 + l16, 1023);
        const short* ep = Eb + m * 64 + quad * 8;
        const s8_t eb0 = *(const s8_t*)ep;
        const s8_t eb1 = *(const s8_t*)(ep + 32);
        f4v g = {0.f, 0.f, 0.f, 0.f};
        g = mfma16(aq[0], eb0, g);
        g = mfma16(aq[1], eb1, g);
#pragma unroll
        for (int r = 0; r < 4; r++)
          gs[(quad * 4 + r) * 152 + t * 16 + l16] = f2bf(g[r]);
      }
    }
    __syncthreads();

    // ---- scores 16x128: (qk + srel)*scale + mask ----
    float p[8][4];
    const int irow = i0 + quad * 4;
#pragma unroll
    for (int jt = 0; jt < 8; jt++) {
      const s8_t k0f = *(const s8_t*)&Ks2[quad][jt * 16 + l16][0];
      const s8_t k1f = *(const s8_t*)&Ks2[4 + quad][jt * 16 + l16][0];
      f4v zz = {0.f, 0.f, 0.f, 0.f};
      zz = mfma16(aq[0], k0f, zz);
      zz = mfma16(aq[1], k1f, zz);
      const int j = j0 + jt * 16 + l16;
      const float kn = kneg[jt * 16 + l16];
#pragma unroll
      for (int r = 0; r < 4; r++) {
        const int rr = quad * 4 + r;
        const float smv = bf2f(gs[rr * 151 + 15 + jt * 16 + l16]);
        const bool causal = (j <= irow + r);
        const float srel = causal ? smv : 0.f;
        const float kk = fbp ? 0.f : (causal ? kn : -1e9f);
        p[jt][r] = (zz[r] + srel) * 0.125f + kk;
      }
    }

    // ---- online softmax ----
    float alpha[4];
#pragma unroll
    for (int r = 0; r < 4; r++) {
      float mx = p[0][r];
#pragma unroll
      for (int jt = 1; jt < 8; jt++) mx = fmaxf(mx, p[jt][r]);
      mx = fmaxf(mx, __shfl_xor(mx, 1));
      mx = fmaxf(mx, __shfl_xor(mx, 2));
      mx = fmaxf(mx, __shfl_xor(mx, 4));
      mx = fmaxf(mx, __shfl_xor(mx, 8));
      const float mnew = fmaxf(m_run[r], mx);
      alpha[r] = expf(m_run[r] - mnew);
      float ps = 0.f;
#pragma unroll
      for (int jt = 0; jt < 8; jt++) {
        p[jt][r] = expf(p[jt][r] - mnew);
        ps += p[jt][r];
      }
      ps += __shfl_xor(ps, 1);
      ps += __shfl_xor(ps, 2);
      ps += __shfl_xor(ps, 4);
      ps += __shfl_xor(ps, 8);
      l_run[r] = l_run[r] * alpha[r] + ps;
      m_run[r] = mnew;
    }

    // ---- P -> LDS (A-layout, overwrites G cols 0..127), rescale O ----
#pragma unroll
    for (int jt = 0; jt < 8; jt++)
#pragma unroll
      for (int r = 0; r < 4; r++)
        gs[(quad * 4 + r) * 152 + jt * 16 + l16] = f2bf(p[jt][r]);
#pragma unroll
    for (int nt = 0; nt < 4; nt++)
#pragma unroll
      for (int r = 0; r < 4; r++)
        o[nt][r] *= alpha[r];

    // ---- O += P @ V (K=128) ----
#pragma unroll
    for (int ks4 = 0; ks4 < 4; ks4++) {
      const s8_t ap = *(const s8_t*)&gs[l16 * 152 + ks4 * 32 + quad * 8];
#pragma unroll
      for (int nt = 0; nt < 4; nt++) {
        const s8_t vf = *(const s8_t*)&Vt[nt * 16 + l16][ks4 * 32 + quad * 8];
        o[nt] = mfma16(ap, vf, o[nt]);
      }
    }
    __syncthreads();
  }

  // ---- epilogue ----
  if (fbp) {
#pragma unroll
    for (int nt = 0; nt < 4; nt++)
#pragma unroll
      for (int r = 0; r < 4; r++) {
        const int i = i0 + quad * 4 + r;
        if (i < fb)
          outb[((long)(b * 1024 + i)) * 1024 + hh * 64 + nt * 16 + l16] =
              f2bf(o[nt][r] / l_run[r]);
      }
  } else if (yy >= 36) {   // itile < 4: single chunk -> direct write
#pragma unroll
    for (int nt = 0; nt < 4; nt++)
#pragma unroll
      for (int r = 0; r < 4; r++) {
        const int i = i0 + quad * 4 + r;
        if (i >= fb)
          outb[((long)(b * 1024 + i)) * 1024 + hh * 64 + nt * 16 + l16] =
              f2bf(o[nt][r] / l_run[r]);
      }
  } else {
    const long part = (long)(bh * 16 + itile) * 4 + cw;
    float* po = PO + part * 4096;
#pragma unroll
    for (int nt = 0; nt < 4; nt++)
#pragma unroll
      for (int r = 0; r < 4; r++) {
        const int row = wave * 16 + quad * 4 + r;
        po[row * 64 + nt * 16 + l16] = o[nt][r];
      }
    if (l16 == 0) {
#pragma unroll
      for (int r = 0; r < 4; r++) {
        const int row = wave * 16 + quad * 4 + r;
        PM[part * 64 + row] = m_run[r];
        PL[part * 64 + row] = l_run[r];
      }
    }
  }
}

// combine partial chunks -> output for itile>=4. grid 384 (32 bh x 12), 256 thr.
__global__ __launch_bounds__(256) void attn_combine(
    const float* __restrict__ PO, const float* __restrict__ PM,
    const float* __restrict__ PL, const int* __restrict__ fnp,
    short* __restrict__ outb) {
  const int id = blockIdx.x;
  const int bh = id / 12, itile = 4 + id % 12;
  const int b = bh >> 4, hh = bh & 15;
  const int nc = (itile >> 2) + 1;
  const int row = threadIdx.x >> 2, seg = (threadIdx.x & 3) << 4;
  const long base = (long)(bh * 16 + itile) * 4;
  const int i = itile * 64 + row;
  if (i < fnp[b]) return;   // fully-masked rows handled by fallback path

  float mv[4];
  float M = -INFINITY;
  for (int c = 0; c < nc; c++) {
    mv[c] = PM[(base + c) * 64 + row];
    M = fmaxf(M, mv[c]);
  }
  f4v acc[4];
#pragma unroll
  for (int t = 0; t < 4; t++) { f4v zz = {0.f, 0.f, 0.f, 0.f}; acc[t] = zz; }
  float l = 0.f;
  for (int c = 0; c < nc; c++) {
    const float w = expf(mv[c] - M);
    l += w * PL[(base + c) * 64 + row];
    const float* po = PO + (base + c) * 4096 + row * 64 + seg;
#pragma unroll
    for (int t = 0; t < 4; t++) {
      const f4v v = *(const f4v*)(po + t * 4);
      acc[t] += w * v;
    }
  }
  const float inv = 1.0f / l;
  short* op = outb + ((long)(b * 1024 + i)) * 1024 + hh * 64 + seg;
#pragma unroll
  for (int t = 0; t < 4; t++) {
    s4_t o = {f2bf(acc[t][0] * inv), f2bf(acc[t][1] * inv),
              f2bf(acc[t][2] * inv), f2bf(acc[t][3] * inv)};
    *(s4_t*)(op + t * 4) = o;
  }
}

// ---------------------------------------------------------------------------
extern "C" void kernel_launch(void* const* d_in, const int* in_sizes, int n_in,
                              void* d_out, int out_size, void* d_ws, size_t ws_size,
                              hipStream_t stream) {
  const int*   x   = (const int*)d_in[0];
  const float* emb = (const float*)d_in[1];
  const float* Wq  = (const float*)d_in[2];
  const float* bq  = (const float*)d_in[3];
  const float* Wk  = (const float*)d_in[4];
  const float* bk  = (const float*)d_in[5];
  const float* Wv  = (const float*)d_in[6];
  const float* bv  = (const float*)d_in[7];
  const float* Wo  = (const float*)d_in[8];
  const float* bo  = (const float*)d_in[9];
  const float* W1  = (const float*)d_in[10];
  const float* b1  = (const float*)d_in[11];
  const float* W2  = (const float*)d_in[12];
  const float* b2  = (const float*)d_in[13];
  const float* g1  = (const float*)d_in[14];
  const float* be1 = (const float*)d_in[15];
  const float* g2  = (const float*)d_in[16];
  const float* be2 = (const float*)d_in[17];
  const float* E   = (const float*)d_in[18];
  const float* Wf  = (const float*)d_in[19];
  const float* bfv = (const float*)d_in[20];

  char* p = (char*)d_ws;
  auto alloc = [&](size_t bytes) {
    char* r = p;
    p += (bytes + 255) & ~(size_t)255;
    return r;
  };
  short* h    = (short*)alloc(2048ull * 1024 * 2);
  short* qkv  = (short*)alloc(2048ull * 3072 * 2);
  short* attn = (short*)alloc(2048ull * 1024 * 2);
  short* tmp  = (short*)alloc(2048ull * 1024 * 2);
  short* mid  = (short*)alloc(2048ull * 512 * 2);
  short* qkvT = (short*)alloc(6ull * 3072 * 1024 * 2);
  short* WoT  = (short*)alloc(6ull * 1024 * 1024 * 2);
  short* W1T  = (short*)alloc(6ull * 512 * 1024 * 2);
  short* W2T  = (short*)alloc(6ull * 1024 * 512 * 2);
  short* WfT  = (short*)alloc(256ull * 1024 * 2);
  short* Ebf  = (short*)alloc(6ull * 1024 * 64 * 2);
  float* qkvB = (float*)alloc(6ull * 3072 * 4);
  int*   fnp  = (int*)alloc(256);
  float* PO   = (float*)alloc(2048ull * 4096 * 4);
  float* PM   = (float*)alloc(2048ull * 64 * 4);
  float* PL   = (float*)alloc(2048ull * 64 * 4);

  prep_weights<<<30976, dim3(32, 8), 0, stream>>>(
      Wq, Wk, Wv, Wo, W1, W2, Wf, qkvT, WoT, W1T, W2T, WfT);
  prep_misc<<<2506, 256, 0, stream>>>(x, emb, E, bq, bk, bv, h, Ebf, qkvB, fnp);

  for (int l = 0; l < 6; l++) {
    const long wOff = (long)l * 1024 * 1024;
    const long w12Off = (long)l * 512 * 1024;
    gemm_lds<128, 128, 2, 2, 1, 0><<<dim3(24, 16), 256, 0, stream>>>(
        h, qkvT + (long)l * 3072 * 1024, qkv, qkvB + l * 3072, 1024, 1024, 1024, 3072);
    attn_main<<<dim3(32, 56), 256, 0, stream>>>(
        qkv, Ebf + (long)l * 1024 * 64, x, fnp, PO, PM, PL, attn);
    attn_combine<<<384, 256, 0, stream>>>(PO, PM, PL, fnp, attn);
    gemm_lds<64, 64, 2, 2, 1, 0><<<dim3(16, 32), 256, 0, stream>>>(
        attn, WoT + wOff, tmp, bo + l * 1024, 1024, 1024, 1024, 1024);
    ln_kernel<<<2048, 256, 0, stream>>>(tmp, tmp, g1 + l * 1024, be1 + l * 1024);
    gemm_lds<64, 64, 2, 2, 1, 1><<<dim3(8, 32), 256, 0, stream>>>(
        tmp, W1T + w12Off, mid, b1 + l * 512, 1024, 1024, 1024, 512);
    gemm_lds<64, 64, 2, 2, 1, 0><<<dim3(16, 32), 256, 0, stream>>>(
        mid, W2T + w12Off, h, b2 + l * 1024, 512, 512, 512, 1024);
    ln_kernel<<<2048, 256, 0, stream>>>(h, h, g2 + l * 1024, be2 + l * 1024);
  }
  gemm_lds<64, 64, 2, 2, 0, 0><<<dim3(4, 32), 256, 0, stream>>>(
      h, WfT, (float*)d_out, bfv, 1024, 1024, 1024, 256);
}